// Round 7
// baseline (493.418 us; speedup 1.0000x reference)
//
#include <hip/hip_runtime.h>
#include <math.h>

// ---------------------------------------------------------------------------
// ActorCriticPolicy fused forward — FP16 in/out, fp32 internal (R6+ verified).
//   E=100, H=256, L=4 res blocks, B=1024, A=256.
//   d_out: logits (1024x256 fp16) then value (1024 fp16).
//
// R16: GEMM k-loop forced to #pragma unroll 1. R15 still spilled (VGPR=32,
// FETCH 112/WRITE 199 MB vs clean 32/71): full unroll let the compiler
// hoist B-loads across 8 k-iterations for ILP, blowing the 32-VGPR half of
// the (512,8) 64-reg split. At 8 waves/EU the TLP already hides the load
// latency, so the hoisting only bought spill. unroll 1 keeps <=2 B-frags +
// 2 A-frags live (~20 regs). Decisive counter: scratch traffic must vanish.
//
// R15: no B-prefetch; policy residual re-read from h16 (z_l IS this layer's
// A matrix; read-before-overwrite by owning thread). Value path keeps fp32
// resf[16] in its own instantiation (32 blocks).
// R14: 8 waves x (32 rows x 32 cols); centralized LN stats (32-thr phase).
// R13/R12 lesson: spill poison — check FETCH/WRITE on every reg change.
// R11: ~225us residue is harness floor. R10: merged grid; logits epilogue.
//
// Wave w of 8: rows 0..31, cols w*32..+31 (2 n-tiles). A-frags from LDS
// h16[32][264]; B-frags from packed global (L2-resident).
// Fragment layouts (R7-verified): A: m=lane&15, k=(lane>>4)*8+j;
// B: n=lane&15, k=(lane>>4)*8+j; C/D: col=lane&15, row=(lane>>4)*4+reg.
//
// Packed layout (f16 units), per net [WIN | L0..L3 | W1head]:
//   policy: 0 win, 32768+l*65536 layers, W1@294912 (16 nt), W2@360448 (7 nt)
//   value:  base 389120: win, layers, W1@+294912 (8 nt). total 716800 f16.
// ---------------------------------------------------------------------------

typedef unsigned short u16;
typedef _Float16 f16;
typedef _Float16 half8 __attribute__((ext_vector_type(8)));
typedef float floatx4 __attribute__((ext_vector_type(4)));

#define E_DIM  100
#define H_DIM  256
#define NLAYER 4
#define BATCH  1024
#define NACT   256
#define NROWS_ACT (BATCH * NACT)
#define LN_EPS 1e-5f

#define NET_WIN  0
#define NET_WL(l) (32768 + (l) * 65536)
#define NET_W1   294912
#define NET_W2P  360448
#define POL_SZ   389120
#define VAL_BASE POL_SZ
#define PACK_TOTAL (POL_SZ + 327680)

#define TROWS 32                         // rows per block
#define ACT_BLOCKS (NROWS_ACT / TROWS)   // 8192
#define OBS_BLOCKS (BATCH / TROWS)       // 32 (policy) + 32 (value)

#define WS_VROWS   16
#define WS_ENCOBS  (16 + NROWS_ACT * 4)
#define WS_PACK    (WS_ENCOBS + BATCH * E_DIM * 4)
#define WS_ENCACT  (WS_PACK + PACK_TOTAL * 2)   // f16[NROWS_ACT * 112] ~ 59 MB

__device__ __forceinline__ u16 f2h_u16(float f) {
  union { u16 u; f16 h; } c; c.h = (f16)f; return c.u;
}

__device__ __forceinline__ float wsum(float v) {
#pragma unroll
  for (int off = 1; off < 64; off <<= 1) v += __shfl_xor(v, off, 64);
  return v;
}

// DPP 16-lane butterfly sum — VALU-only, no DS pipe traffic.
template <int CTRL>
__device__ __forceinline__ float dpp_add(float v) {
  const int t = __builtin_amdgcn_update_dpp(0, __float_as_int(v), CTRL, 0xF, 0xF, true);
  return v + __int_as_float(t);
}
__device__ __forceinline__ float dpp_red16(float v) {
  v = dpp_add<0xB1>(v);    // quad_perm [1,0,3,2]  (xor 1)
  v = dpp_add<0x4E>(v);    // quad_perm [2,3,0,1]  (xor 2)
  v = dpp_add<0x141>(v);   // row_half_mirror      (pairs 4-blocks)
  v = dpp_add<0x140>(v);   // row_mirror           (pairs 8-blocks)
  return v;
}

__global__ void zero_counter_kernel(int* counter) { *counter = 0; }

// Wave-aggregated compaction (R11; neutral vs per-lane atomic but keep).
__global__ void compact_kernel(const int* __restrict__ mask, int n,
                               int* __restrict__ counter,
                               int* __restrict__ rows,
                               u16* __restrict__ logits)
{
  const int i = blockIdx.x * blockDim.x + threadIdx.x;
  const int lane = threadIdx.x & 63;
  bool valid = false;
  if (i < n) {
    valid = (mask[i] != 0);
    if (!valid) logits[i] = (u16)0xFBFF;   // -65504, finite fp16 -inf stand-in
  }
  const unsigned long long bal = __ballot(valid);
  const int cnt = __popcll(bal);
  int base = 0;
  if (lane == 0 && cnt) base = atomicAdd(counter, cnt);
  base = __shfl(base, 0, 64);
  if (valid) {
    const int off = __popcll(bal & ((1ull << lane) - 1ull));
    rows[base + off] = i;
  }
}

__device__ __forceinline__ f16 pack_elem(const f16* __restrict__ W, int li,
                                         int K, int N, int Np)
{
  const int j = li & 7, lane = (li >> 3) & 63, tile = li >> 9;
  const int ntiles = Np >> 4;
  const int k0 = (tile / ntiles) * 32, n0 = (tile % ntiles) * 16;
  const int k = k0 + ((lane >> 4) << 3) + j, n = n0 + (lane & 15);
  return (k < K && n < N) ? W[k * N + n] : (f16)0.f;
}

__global__ void pack_all_kernel(
    const f16* __restrict__ pw_in, const f16* __restrict__ pW,
    const f16* __restrict__ po_w1, const f16* __restrict__ po_w2,
    const f16* __restrict__ vw_in, const f16* __restrict__ vW,
    const f16* __restrict__ vo_w1, f16* __restrict__ dst)
{
  const int i = blockIdx.x * blockDim.x + threadIdx.x;
  if (i >= PACK_TOTAL) return;
  f16 v;
  if (i < 32768)        v = pack_elem(pw_in, i, E_DIM, H_DIM, 256);
  else if (i < 294912) { const int r = i - 32768, l = r >> 16;
                         v = pack_elem(pW + (size_t)l * 65536, r & 65535, 256, 256, 256); }
  else if (i < 360448)  v = pack_elem(po_w1, i - 294912, 256, 256, 256);
  else if (i < 389120)  v = pack_elem(po_w2, i - 360448, 256, E_DIM, 112);
  else if (i < 421888)  v = pack_elem(vw_in, i - 389120, E_DIM, H_DIM, 256);
  else if (i < 684032) { const int r = i - 421888, l = r >> 16;
                         v = pack_elem(vW + (size_t)l * 65536, r & 65535, 256, 256, 256); }
  else                  v = pack_elem(vo_w1, i - 684032, 256, 128, 128);
  dst[i] = v;
}

// wave GEMM: KT k-steps of 32, NTC n-tiles, NTA = total n-tiles in the
// packed matrix. R16: k-loop NOT unrolled — keeps only one k-step of
// B/A fragments live (~20 VGPRs) so the (512,8) 32-VGPR half fits.
// 8 waves/SIMD provide the latency hiding (TLP, not ILP).
template <int KT, int NTC, int NTA>
__device__ __forceinline__ void wave_gemm_t(
    const f16* __restrict__ pw, const f16* __restrict__ h16,
    int q, int l15, int lane, int nt_base,
    floatx4 acc0[], floatx4 acc1[])
{
  const f16* pl = pw + (size_t)nt_base * 512 + lane * 8;
  const f16* pa = h16 + l15 * 264 + q * 8;
#pragma unroll 1
  for (int k = 0; k < KT; ++k) {
    half8 bc[NTC];
#pragma unroll
    for (int t = 0; t < NTC; ++t)
      bc[t] = *(const half8*)(pl + t * 512);
    const half8 a0 = *(const half8*)(pa);
    const half8 a1 = *(const half8*)(pa + 16 * 264);
#pragma unroll
    for (int t = 0; t < NTC; ++t) {
      acc0[t] = __builtin_amdgcn_mfma_f32_16x16x32_f16(a0, bc[t], acc0[t], 0, 0, 0);
      acc1[t] = __builtin_amdgcn_mfma_f32_16x16x32_f16(a1, bc[t], acc1[t], 0, 0, 0);
    }
    pl += (size_t)NTA * 512;
    pa += 32;
  }
}

// trunk: input layer + NLAYER residual layers.
// RLDS=true: residual re-read from h16 (policy). false: fp32 resf (value).
// 8 waves; wave w: rows 0..31, cols w*32..+31. 3 barriers/layer.
template <bool RLDS>
__device__ __forceinline__ void run_trunk(
    const f16* __restrict__ packN,
    const f16* __restrict__ b_in, const f16* __restrict__ g_in, const f16* __restrict__ be_in,
    const f16* __restrict__ Br, const f16* __restrict__ Gr, const f16* __restrict__ Ber,
    f16* __restrict__ h16, float2 (*red)[8], float2* __restrict__ stats,
    floatx4 acc[2][2], float* __restrict__ resf,
    int tid, int q, int l15, int w, int n0)
{
#pragma unroll 1
  for (int l = 0; l <= NLAYER; ++l) {
    const f16* pw; const f16* bias; const f16* g; const f16* be;
    if (l == 0) { pw = packN + NET_WIN; bias = b_in; g = g_in; be = be_in; }
    else {
      pw = packN + NET_WL(l - 1); bias = Br + (l - 1) * H_DIM;
      g = Gr + (l - 1) * H_DIM;   be = Ber + (l - 1) * H_DIM;
    }
#pragma unroll
    for (int t = 0; t < 2; ++t) {
      const float bv = (float)bias[n0 + t * 16 + l15];
      acc[0][t] = (floatx4){bv, bv, bv, bv};
      acc[1][t] = acc[0][t];
    }
    if (l == 0) wave_gemm_t<4, 2, 16>(pw, h16, q, l15, tid & 63, w * 2, acc[0], acc[1]);
    else        wave_gemm_t<8, 2, 16>(pw, h16, q, l15, tid & 63, w * 2, acc[0], acc[1]);

    // partial sums over this wave's 32 cols
#pragma unroll
    for (int mt = 0; mt < 2; ++mt)
#pragma unroll
      for (int reg = 0; reg < 4; ++reg) {
        const float v0 = fmaxf(acc[mt][0][reg], 0.f);
        const float v1 = fmaxf(acc[mt][1][reg], 0.f);
        acc[mt][0][reg] = v0; acc[mt][1][reg] = v1;   // keep relu'd
        float s  = dpp_red16(v0 + v1);
        float s2 = dpp_red16(v0 * v0 + v1 * v1);
        if (l15 == 0) red[mt * 16 + q * 4 + reg][w] = (float2){s, s2};
      }
    __syncthreads();

    // centralized row stats: 32 threads, one row each
    if (tid < TROWS) {
      const float4* rp = (const float4*)&red[tid][0];
      const float4 r0 = rp[0], r1 = rp[1], r2 = rp[2], r3 = rp[3];
      const float s  = r0.x + r0.z + r1.x + r1.z + r2.x + r2.z + r3.x + r3.z;
      const float s2 = r0.y + r0.w + r1.y + r1.w + r2.y + r2.w + r3.y + r3.w;
      const float mean = s * (1.f / 256.f);
      const float var  = s2 * (1.f / 256.f) - mean * mean;
      stats[tid] = (float2){mean, 1.f / sqrtf(var + LN_EPS)};
    }
    __syncthreads();

    const float gf0 = (float)g[n0 + l15],       gf1 = (float)g[n0 + 16 + l15];
    const float bf0 = (float)be[n0 + l15],      bf1 = (float)be[n0 + 16 + l15];
#pragma unroll
    for (int mt = 0; mt < 2; ++mt)
#pragma unroll
      for (int reg = 0; reg < 4; ++reg) {
        const int R = mt * 16 + q * 4 + reg;
        const float2 st = stats[R];
#pragma unroll
        for (int t = 0; t < 2; ++t) {
          const int col = n0 + t * 16 + l15;
          const float vv = (acc[mt][t][reg] - st.x) * st.y *
                           (t == 0 ? gf0 : gf1) + (t == 0 ? bf0 : bf1);
          float rprev;
          if (l == 0) rprev = 0.f;
          else if (RLDS) rprev = (float)h16[R * 264 + col];   // z_l lives here
          else rprev = resf[(mt * 2 + t) * 4 + reg];
          const float r = rprev + vv;
          if (!RLDS) resf[(mt * 2 + t) * 4 + reg] = r;
          h16[R * 264 + col] = (f16)r;
        }
      }
    __syncthreads();
  }
}

// policy heads: h1 = relu(h @ w1 + b1); enc = h1 @ w2 + b2 -> encf (32x112 f32)
__device__ __forceinline__ void policy_heads(
    const f16* __restrict__ packN,
    const f16* __restrict__ b1, const f16* __restrict__ b2,
    f16* __restrict__ h16, floatx4 acc[2][2],
    int tid, int q, int l15, int w, int n0)
{
#pragma unroll
  for (int t = 0; t < 2; ++t) {
    const float bv = (float)b1[n0 + t * 16 + l15];
    acc[0][t] = (floatx4){bv, bv, bv, bv};
    acc[1][t] = acc[0][t];
  }
  wave_gemm_t<8, 2, 16>(packN + NET_W1, h16, q, l15, tid & 63, w * 2, acc[0], acc[1]);
  __syncthreads();
#pragma unroll
  for (int mt = 0; mt < 2; ++mt)
#pragma unroll
    for (int reg = 0; reg < 4; ++reg) {
      const int R = mt * 16 + q * 4 + reg;
#pragma unroll
      for (int t = 0; t < 2; ++t)
        h16[R * 264 + n0 + t * 16 + l15] = (f16)fmaxf(acc[mt][t][reg], 0.f);
    }
  __syncthreads();

  // W2: 7 n-tiles; waves 0..6 take one tile each
  if (w < 7) {
    const int col = w * 16 + l15;
    const float bv = (col < E_DIM) ? (float)b2[col] : 0.f;
    acc[0][0] = (floatx4){bv, bv, bv, bv};
    acc[1][0] = acc[0][0];
    wave_gemm_t<8, 1, 7>(packN + NET_W2P, h16, q, l15, tid & 63, w, acc[0], acc[1]);
  }
  __syncthreads();

  float* encf = (float*)h16;   // 32 x 112 fp32 (14336 B <= 16896 B)
  if (w < 7) {
#pragma unroll
    for (int mt = 0; mt < 2; ++mt)
#pragma unroll
      for (int reg = 0; reg < 4; ++reg) {
        const int R = mt * 16 + q * 4 + reg;
        encf[R * 112 + w * 16 + l15] = acc[mt][0][reg];
      }
  }
  __syncthreads();
}

// Merged trunk kernel (8 waves, 32 rows per block, <=64 unified regs/wave).
//  blockIdx 0..31  : policy obs-encode (1024 rows)  -> enc_obs (f32)
//  blockIdx 32..63 : value net (1024 rows)          -> value   (f16)
//  blockIdx 64..   : act-encode on compacted rows   -> enc_act (f16, ws)
__global__ __launch_bounds__(512, 8)
void trunk_kernel(
    const f16* __restrict__ obs, const f16* __restrict__ xact,
    const int* __restrict__ vrows, const int* __restrict__ counter,
    const f16* __restrict__ packP, const f16* __restrict__ packV,
    // policy params
    const f16* __restrict__ pb_in, const f16* __restrict__ pg_in, const f16* __restrict__ pbe_in,
    const f16* __restrict__ pB, const f16* __restrict__ pG, const f16* __restrict__ pBe,
    const f16* __restrict__ po_b1, const f16* __restrict__ po_b2,
    // value params
    const f16* __restrict__ vb_in, const f16* __restrict__ vg_in, const f16* __restrict__ vbe_in,
    const f16* __restrict__ vB, const f16* __restrict__ vG, const f16* __restrict__ vBe,
    const f16* __restrict__ vo_b1, const f16* __restrict__ vo_b2, const f16* __restrict__ vo_w2,
    float* __restrict__ enc_obs_out, f16* __restrict__ enc_act_out,
    u16* __restrict__ value_out)
{
  __shared__ __align__(16) f16 h16[TROWS * 264];
  __shared__ __align__(16) float2 red[TROWS][8];
  __shared__ float2 stats[TROWS];

  const int tid  = threadIdx.x;
  const int lane = tid & 63;
  const int w    = tid >> 6;          // 0..7
  const int l15 = lane & 15, q = lane >> 4;
  const int n0 = w * 32;              // wave cols: w*32 .. w*32+31

  floatx4 acc[2][2];

  if (blockIdx.x >= 2 * OBS_BLOCKS) {
    // ---------------- act-encode role ----------------
    const int count = *counter;
    const int base = (blockIdx.x - 2 * OBS_BLOCKS) * TROWS;
    if (base >= count) return;

    for (int idx = tid; idx < TROWS * 128; idx += 512) {
      const int r = idx >> 7, c = idx & 127;
      const int gr = base + r;
      f16 v = (f16)0.f;
      if (c < E_DIM && gr < count) v = xact[(size_t)vrows[gr] * E_DIM + c];
      h16[r * 264 + c] = v;
    }
    __syncthreads();

    run_trunk<true>(packP, pb_in, pg_in, pbe_in, pB, pG, pBe, h16, red, stats,
                    acc, nullptr, tid, q, l15, w, n0);
    policy_heads(packP, po_b1, po_b2, h16, acc, tid, q, l15, w, n0);

    const float* encf = (const float*)h16;
    for (int idx = tid; idx < TROWS * 112; idx += 512) {
      const int r = idx / 112, c = idx - r * 112;
      enc_act_out[(size_t)(base + r) * 112 + c] = (f16)encf[r * 112 + c];
    }
    return;
  }

  // ---------------- obs / value roles ----------------
  const bool isv = blockIdx.x >= OBS_BLOCKS;
  const int base = (isv ? (blockIdx.x - OBS_BLOCKS) : blockIdx.x) * TROWS;

  for (int idx = tid; idx < TROWS * 128; idx += 512) {
    const int r = idx >> 7, c = idx & 127;
    h16[r * 264 + c] = (c < E_DIM) ? obs[(size_t)(base + r) * E_DIM + c] : (f16)0.f;
  }
  __syncthreads();

  if (!isv) {
    run_trunk<true>(packP, pb_in, pg_in, pbe_in, pB, pG, pBe, h16, red, stats,
                    acc, nullptr, tid, q, l15, w, n0);
    policy_heads(packP, po_b1, po_b2, h16, acc, tid, q, l15, w, n0);
    const float* encf = (const float*)h16;
    for (int idx = tid; idx < TROWS * E_DIM; idx += 512) {
      const int r = idx / E_DIM, c = idx - r * E_DIM;
      enc_obs_out[(size_t)(base + r) * E_DIM + c] = encf[r * 112 + c];
    }
  } else {
    float resf[16];
    run_trunk<false>(packV, vb_in, vg_in, vbe_in, vB, vG, vBe, h16, red, stats,
                     acc, resf, tid, q, l15, w, n0);
    // value head1: relu(h @ vo_w1 + vo_b1), N=128 = 8 n-tiles, 1 per wave
    {
      const float bv = (float)vo_b1[w * 16 + l15];
      acc[0][0] = (floatx4){bv, bv, bv, bv};
      acc[1][0] = acc[0][0];
    }
    wave_gemm_t<8, 1, 8>(packV + NET_W1, h16, q, l15, lane, w, acc[0], acc[1]);
    __syncthreads();
    float* encf = (float*)h16;   // 32 x 128 fp32 (16384 B <= 16896 B)
#pragma unroll
    for (int mt = 0; mt < 2; ++mt)
#pragma unroll
      for (int reg = 0; reg < 4; ++reg) {
        const int R = mt * 16 + q * 4 + reg;
        encf[R * 128 + w * 16 + l15] = fmaxf(acc[mt][0][reg], 0.f);
      }
    __syncthreads();
    const float w2a = (float)vo_w2[lane], w2b = (float)vo_w2[lane + 64];
    const float b2v = (float)vo_b2[0];
    for (int j = 0; j < 4; ++j) {
      const int r = w * 4 + j;
      const float p = encf[r * 128 + lane] * w2a + encf[r * 128 + lane + 64] * w2b;
      const float tot = wsum(p);
      if (lane == 0) value_out[base + r] = f2h_u16(tot + b2v);
    }
  }
}

// epilogue: logits[vrow] = (enc_obs[bb] . enc_act[gr]) / sqrt(E)
__global__ __launch_bounds__(256)
void logits_kernel(const int* __restrict__ vrows, const int* __restrict__ counter,
                   const f16* __restrict__ enc_act, const float* __restrict__ enc_obs,
                   u16* __restrict__ logits)
{
  const int count = *counter;
  const int lane = threadIdx.x & 63;
  const int nw = (gridDim.x * blockDim.x) >> 6;
  for (int gr = (blockIdx.x * blockDim.x + threadIdx.x) >> 6; gr < count; gr += nw) {
    const int vrow = vrows[gr];
    const int bb = vrow >> 8;   // A = 256
    const float* ob = enc_obs + (size_t)bb * E_DIM;
    const f16*   ar = enc_act + (size_t)gr * 112;
    float p = (float)ar[lane] * ob[lane];
    if (lane + 64 < E_DIM) p += (float)ar[lane + 64] * ob[lane + 64];
    const float tot = wsum(p);
    if (lane == 0) logits[vrow] = f2h_u16(tot * 0.1f);   // 1/sqrt(100)
  }
}

// ============================ launch =======================================
extern "C" void kernel_launch(void* const* d_in, const int* in_sizes, int n_in,
                              void* d_out, int out_size, void* d_ws, size_t ws_size,
                              hipStream_t stream)
{
  const f16* obs   = (const f16*)d_in[0];
  const f16* actE  = (const f16*)d_in[1];
  const int* mask  = (const int*)d_in[2];
  const f16* pw_in = (const f16*)d_in[3];
  const f16* pb_in = (const f16*)d_in[4];
  const f16* pg_in = (const f16*)d_in[5];
  const f16* pbe_in= (const f16*)d_in[6];
  const f16* pW    = (const f16*)d_in[7];
  const f16* pB    = (const f16*)d_in[8];
  const f16* pG    = (const f16*)d_in[9];
  const f16* pBe   = (const f16*)d_in[10];
  const f16* po_w1 = (const f16*)d_in[11];
  const f16* po_b1 = (const f16*)d_in[12];
  const f16* po_w2 = (const f16*)d_in[13];
  const f16* po_b2 = (const f16*)d_in[14];
  const f16* vw_in = (const f16*)d_in[15];
  const f16* vb_in = (const f16*)d_in[16];
  const f16* vg_in = (const f16*)d_in[17];
  const f16* vbe_in= (const f16*)d_in[18];
  const f16* vW    = (const f16*)d_in[19];
  const f16* vB    = (const f16*)d_in[20];
  const f16* vG    = (const f16*)d_in[21];
  const f16* vBe   = (const f16*)d_in[22];
  const f16* vo_w1 = (const f16*)d_in[23];
  const f16* vo_b1 = (const f16*)d_in[24];
  const f16* vo_w2 = (const f16*)d_in[25];
  const f16* vo_b2 = (const f16*)d_in[26];

  u16* logits = (u16*)d_out;
  u16* value  = (u16*)d_out + NROWS_ACT;

  int*   counter = (int*)d_ws;
  int*   vrows   = (int*)((char*)d_ws + WS_VROWS);
  float* enc_obs = (float*)((char*)d_ws + WS_ENCOBS);
  f16*   packW   = (f16*)((char*)d_ws + WS_PACK);
  f16*   enc_act = (f16*)((char*)d_ws + WS_ENCACT);

  zero_counter_kernel<<<1, 1, 0, stream>>>(counter);
  compact_kernel<<<NROWS_ACT / 256, 256, 0, stream>>>(mask, NROWS_ACT, counter,
                                                      vrows, logits);
  pack_all_kernel<<<(PACK_TOTAL + 255) / 256, 256, 0, stream>>>(
      pw_in, pW, po_w1, po_w2, vw_in, vW, vo_w1, packW);

  trunk_kernel<<<ACT_BLOCKS + 2 * OBS_BLOCKS, 512, 0, stream>>>(
      obs, actE, vrows, counter, packW, packW + VAL_BASE,
      pb_in, pg_in, pbe_in, pB, pG, pBe, po_b1, po_b2,
      vb_in, vg_in, vbe_in, vB, vG, vBe, vo_b1, vo_b2, vo_w2,
      enc_obs, enc_act, value);

  logits_kernel<<<2048, 256, 0, stream>>>(vrows, counter, enc_act, enc_obs, logits);
}

// Round 8
// 478.883 us; speedup vs baseline: 1.0304x; 1.0304x over previous
//
#include <hip/hip_runtime.h>
#include <math.h>

// ---------------------------------------------------------------------------
// ActorCriticPolicy fused forward — FP16 in/out, fp32 internal (R6+ verified).
//   E=100, H=256, L=4 res blocks, B=1024, A=256.
//   d_out: logits (1024x256 fp16) then value (1024 fp16).
//
// R17: 6 waves/EU sweet spot. R14-R16 showed the (512,8) 64-reg cap always
// spills (~100-250MB scratch, trunk 262-267) while clean 4 waves/EU = 297.
// (512,6) -> 80-reg cap fits the FULL fast inner loop with zero spill:
// acc 16 AGPR + bc 8 + bn 8 (depth-1 B prefetch restored) + a 8 + res16 8
// (policy residual back in registers — removes 128 scalar ds_read_u16 per
// block-layer that R15's h16 re-read added) + temps ~12 ≈ 60 <= 80.
// 24 waves/CU (~75% occ). Decisive counters: VGPR ~56-64 (not 32),
// WRITE ~71MB / FETCH ~32MB (scratch gone), trunk -> ~230-240us.
//
// R16: unroll-1 k-loop (compiler hoisting was the spill source at cap 64).
// R14: 8 waves x (32 rows x 32 cols); centralized LN stats (32-thr phase).
// R13/R12 lesson: spill poison — check FETCH/WRITE on every reg change.
// R11: ~225us residue is harness floor. R10: merged grid; logits epilogue.
//
// Wave w of 8: rows 0..31, cols w*32..+31 (2 n-tiles). A-frags from LDS
// h16[32][264]; B-frags from packed global (L2-resident), depth-1 prefetch.
// Fragment layouts (R7-verified): A: m=lane&15, k=(lane>>4)*8+j;
// B: n=lane&15, k=(lane>>4)*8+j; C/D: col=lane&15, row=(lane>>4)*4+reg.
//
// Packed layout (f16 units), per net [WIN | L0..L3 | W1head]:
//   policy: 0 win, 32768+l*65536 layers, W1@294912 (16 nt), W2@360448 (7 nt)
//   value:  base 389120: win, layers, W1@+294912 (8 nt). total 716800 f16.
// ---------------------------------------------------------------------------

typedef unsigned short u16;
typedef _Float16 f16;
typedef _Float16 half8 __attribute__((ext_vector_type(8)));
typedef float floatx4 __attribute__((ext_vector_type(4)));

#define E_DIM  100
#define H_DIM  256
#define NLAYER 4
#define BATCH  1024
#define NACT   256
#define NROWS_ACT (BATCH * NACT)
#define LN_EPS 1e-5f

#define NET_WIN  0
#define NET_WL(l) (32768 + (l) * 65536)
#define NET_W1   294912
#define NET_W2P  360448
#define POL_SZ   389120
#define VAL_BASE POL_SZ
#define PACK_TOTAL (POL_SZ + 327680)

#define TROWS 32                         // rows per block
#define ACT_BLOCKS (NROWS_ACT / TROWS)   // 8192
#define OBS_BLOCKS (BATCH / TROWS)       // 32 (policy) + 32 (value)

#define WS_VROWS   16
#define WS_ENCOBS  (16 + NROWS_ACT * 4)
#define WS_PACK    (WS_ENCOBS + BATCH * E_DIM * 4)
#define WS_ENCACT  (WS_PACK + PACK_TOTAL * 2)   // f16[NROWS_ACT * 112] ~ 59 MB

__device__ __forceinline__ u16 f2h_u16(float f) {
  union { u16 u; f16 h; } c; c.h = (f16)f; return c.u;
}

__device__ __forceinline__ float wsum(float v) {
#pragma unroll
  for (int off = 1; off < 64; off <<= 1) v += __shfl_xor(v, off, 64);
  return v;
}

// DPP 16-lane butterfly sum — VALU-only, no DS pipe traffic.
template <int CTRL>
__device__ __forceinline__ float dpp_add(float v) {
  const int t = __builtin_amdgcn_update_dpp(0, __float_as_int(v), CTRL, 0xF, 0xF, true);
  return v + __int_as_float(t);
}
__device__ __forceinline__ float dpp_red16(float v) {
  v = dpp_add<0xB1>(v);    // quad_perm [1,0,3,2]  (xor 1)
  v = dpp_add<0x4E>(v);    // quad_perm [2,3,0,1]  (xor 2)
  v = dpp_add<0x141>(v);   // row_half_mirror      (pairs 4-blocks)
  v = dpp_add<0x140>(v);   // row_mirror           (pairs 8-blocks)
  return v;
}

__global__ void zero_counter_kernel(int* counter) { *counter = 0; }

// Wave-aggregated compaction (R11; neutral vs per-lane atomic but keep).
__global__ void compact_kernel(const int* __restrict__ mask, int n,
                               int* __restrict__ counter,
                               int* __restrict__ rows,
                               u16* __restrict__ logits)
{
  const int i = blockIdx.x * blockDim.x + threadIdx.x;
  const int lane = threadIdx.x & 63;
  bool valid = false;
  if (i < n) {
    valid = (mask[i] != 0);
    if (!valid) logits[i] = (u16)0xFBFF;   // -65504, finite fp16 -inf stand-in
  }
  const unsigned long long bal = __ballot(valid);
  const int cnt = __popcll(bal);
  int base = 0;
  if (lane == 0 && cnt) base = atomicAdd(counter, cnt);
  base = __shfl(base, 0, 64);
  if (valid) {
    const int off = __popcll(bal & ((1ull << lane) - 1ull));
    rows[base + off] = i;
  }
}

__device__ __forceinline__ f16 pack_elem(const f16* __restrict__ W, int li,
                                         int K, int N, int Np)
{
  const int j = li & 7, lane = (li >> 3) & 63, tile = li >> 9;
  const int ntiles = Np >> 4;
  const int k0 = (tile / ntiles) * 32, n0 = (tile % ntiles) * 16;
  const int k = k0 + ((lane >> 4) << 3) + j, n = n0 + (lane & 15);
  return (k < K && n < N) ? W[k * N + n] : (f16)0.f;
}

__global__ void pack_all_kernel(
    const f16* __restrict__ pw_in, const f16* __restrict__ pW,
    const f16* __restrict__ po_w1, const f16* __restrict__ po_w2,
    const f16* __restrict__ vw_in, const f16* __restrict__ vW,
    const f16* __restrict__ vo_w1, f16* __restrict__ dst)
{
  const int i = blockIdx.x * blockDim.x + threadIdx.x;
  if (i >= PACK_TOTAL) return;
  f16 v;
  if (i < 32768)        v = pack_elem(pw_in, i, E_DIM, H_DIM, 256);
  else if (i < 294912) { const int r = i - 32768, l = r >> 16;
                         v = pack_elem(pW + (size_t)l * 65536, r & 65535, 256, 256, 256); }
  else if (i < 360448)  v = pack_elem(po_w1, i - 294912, 256, 256, 256);
  else if (i < 389120)  v = pack_elem(po_w2, i - 360448, 256, E_DIM, 112);
  else if (i < 421888)  v = pack_elem(vw_in, i - 389120, E_DIM, H_DIM, 256);
  else if (i < 684032) { const int r = i - 421888, l = r >> 16;
                         v = pack_elem(vW + (size_t)l * 65536, r & 65535, 256, 256, 256); }
  else                  v = pack_elem(vo_w1, i - 684032, 256, 128, 128);
  dst[i] = v;
}

// wave GEMM: KT k-steps of 32, NTC n-tiles, NTA = total n-tiles in the
// packed matrix. unroll-1 k-loop (R16) + depth-1 B register prefetch (R17):
// one k-step of A/B live plus one prefetched B (~24 VGPRs).
template <int KT, int NTC, int NTA>
__device__ __forceinline__ void wave_gemm_t(
    const f16* __restrict__ pw, const f16* __restrict__ h16,
    int q, int l15, int lane, int nt_base,
    floatx4 acc0[], floatx4 acc1[])
{
  const f16* pl = pw + (size_t)nt_base * 512 + lane * 8;
  const f16* pa = h16 + l15 * 264 + q * 8;
  half8 bc[NTC];
#pragma unroll
  for (int t = 0; t < NTC; ++t) bc[t] = *(const half8*)(pl + t * 512);
#pragma unroll 1
  for (int k = 0; k < KT; ++k) {
    half8 bn[NTC];
    const f16* pln = pl + (size_t)NTA * 512;
    if (k + 1 < KT) {
#pragma unroll
      for (int t = 0; t < NTC; ++t) bn[t] = *(const half8*)(pln + t * 512);
    }
    const half8 a0 = *(const half8*)(pa);
    const half8 a1 = *(const half8*)(pa + 16 * 264);
#pragma unroll
    for (int t = 0; t < NTC; ++t) {
      acc0[t] = __builtin_amdgcn_mfma_f32_16x16x32_f16(a0, bc[t], acc0[t], 0, 0, 0);
      acc1[t] = __builtin_amdgcn_mfma_f32_16x16x32_f16(a1, bc[t], acc1[t], 0, 0, 0);
    }
    if (k + 1 < KT) {
#pragma unroll
      for (int t = 0; t < NTC; ++t) bc[t] = bn[t];
    }
    pl = pln;
    pa += 32;
  }
}

// trunk: input layer + NLAYER residual layers.
// RREG=true: residual in f16 registers (policy). false: fp32 resf (value).
// 8 waves; wave w: rows 0..31, cols w*32..+31. 3 barriers/layer.
template <bool RREG>
__device__ __forceinline__ void run_trunk(
    const f16* __restrict__ packN,
    const f16* __restrict__ b_in, const f16* __restrict__ g_in, const f16* __restrict__ be_in,
    const f16* __restrict__ Br, const f16* __restrict__ Gr, const f16* __restrict__ Ber,
    f16* __restrict__ h16, float2 (*red)[8], float2* __restrict__ stats,
    floatx4 acc[2][2], float* __restrict__ resf, f16* __restrict__ res16,
    int tid, int q, int l15, int w, int n0)
{
#pragma unroll 1
  for (int l = 0; l <= NLAYER; ++l) {
    const f16* pw; const f16* bias; const f16* g; const f16* be;
    if (l == 0) { pw = packN + NET_WIN; bias = b_in; g = g_in; be = be_in; }
    else {
      pw = packN + NET_WL(l - 1); bias = Br + (l - 1) * H_DIM;
      g = Gr + (l - 1) * H_DIM;   be = Ber + (l - 1) * H_DIM;
    }
#pragma unroll
    for (int t = 0; t < 2; ++t) {
      const float bv = (float)bias[n0 + t * 16 + l15];
      acc[0][t] = (floatx4){bv, bv, bv, bv};
      acc[1][t] = acc[0][t];
    }
    if (l == 0) wave_gemm_t<4, 2, 16>(pw, h16, q, l15, tid & 63, w * 2, acc[0], acc[1]);
    else        wave_gemm_t<8, 2, 16>(pw, h16, q, l15, tid & 63, w * 2, acc[0], acc[1]);

    // partial sums over this wave's 32 cols
#pragma unroll
    for (int mt = 0; mt < 2; ++mt)
#pragma unroll
      for (int reg = 0; reg < 4; ++reg) {
        const float v0 = fmaxf(acc[mt][0][reg], 0.f);
        const float v1 = fmaxf(acc[mt][1][reg], 0.f);
        acc[mt][0][reg] = v0; acc[mt][1][reg] = v1;   // keep relu'd
        float s  = dpp_red16(v0 + v1);
        float s2 = dpp_red16(v0 * v0 + v1 * v1);
        if (l15 == 0) red[mt * 16 + q * 4 + reg][w] = (float2){s, s2};
      }
    __syncthreads();

    // centralized row stats: 32 threads, one row each
    if (tid < TROWS) {
      const float4* rp = (const float4*)&red[tid][0];
      const float4 r0 = rp[0], r1 = rp[1], r2 = rp[2], r3 = rp[3];
      const float s  = r0.x + r0.z + r1.x + r1.z + r2.x + r2.z + r3.x + r3.z;
      const float s2 = r0.y + r0.w + r1.y + r1.w + r2.y + r2.w + r3.y + r3.w;
      const float mean = s * (1.f / 256.f);
      const float var  = s2 * (1.f / 256.f) - mean * mean;
      stats[tid] = (float2){mean, 1.f / sqrtf(var + LN_EPS)};
    }
    __syncthreads();

    const float gf0 = (float)g[n0 + l15],       gf1 = (float)g[n0 + 16 + l15];
    const float bf0 = (float)be[n0 + l15],      bf1 = (float)be[n0 + 16 + l15];
#pragma unroll
    for (int mt = 0; mt < 2; ++mt)
#pragma unroll
      for (int reg = 0; reg < 4; ++reg) {
        const int R = mt * 16 + q * 4 + reg;
        const float2 st = stats[R];
#pragma unroll
        for (int t = 0; t < 2; ++t) {
          const int col = n0 + t * 16 + l15;
          const int ri = (mt * 2 + t) * 4 + reg;
          const float vv = (acc[mt][t][reg] - st.x) * st.y *
                           (t == 0 ? gf0 : gf1) + (t == 0 ? bf0 : bf1);
          float rprev;
          if (l == 0) rprev = 0.f;
          else rprev = RREG ? (float)res16[ri] : resf[ri];
          const float r = rprev + vv;
          if (RREG) res16[ri] = (f16)r; else resf[ri] = r;
          h16[R * 264 + col] = (f16)r;
        }
      }
    __syncthreads();
  }
}

// policy heads: h1 = relu(h @ w1 + b1); enc = h1 @ w2 + b2 -> encf (32x112 f32)
__device__ __forceinline__ void policy_heads(
    const f16* __restrict__ packN,
    const f16* __restrict__ b1, const f16* __restrict__ b2,
    f16* __restrict__ h16, floatx4 acc[2][2],
    int tid, int q, int l15, int w, int n0)
{
#pragma unroll
  for (int t = 0; t < 2; ++t) {
    const float bv = (float)b1[n0 + t * 16 + l15];
    acc[0][t] = (floatx4){bv, bv, bv, bv};
    acc[1][t] = acc[0][t];
  }
  wave_gemm_t<8, 2, 16>(packN + NET_W1, h16, q, l15, tid & 63, w * 2, acc[0], acc[1]);
  __syncthreads();
#pragma unroll
  for (int mt = 0; mt < 2; ++mt)
#pragma unroll
    for (int reg = 0; reg < 4; ++reg) {
      const int R = mt * 16 + q * 4 + reg;
#pragma unroll
      for (int t = 0; t < 2; ++t)
        h16[R * 264 + n0 + t * 16 + l15] = (f16)fmaxf(acc[mt][t][reg], 0.f);
    }
  __syncthreads();

  // W2: 7 n-tiles; waves 0..6 take one tile each
  if (w < 7) {
    const int col = w * 16 + l15;
    const float bv = (col < E_DIM) ? (float)b2[col] : 0.f;
    acc[0][0] = (floatx4){bv, bv, bv, bv};
    acc[1][0] = acc[0][0];
    wave_gemm_t<8, 1, 7>(packN + NET_W2P, h16, q, l15, tid & 63, w, acc[0], acc[1]);
  }
  __syncthreads();

  float* encf = (float*)h16;   // 32 x 112 fp32 (14336 B <= 16896 B)
  if (w < 7) {
#pragma unroll
    for (int mt = 0; mt < 2; ++mt)
#pragma unroll
      for (int reg = 0; reg < 4; ++reg) {
        const int R = mt * 16 + q * 4 + reg;
        encf[R * 112 + w * 16 + l15] = acc[mt][0][reg];
      }
  }
  __syncthreads();
}

// Merged trunk kernel (8 waves, 32 rows per block, 80-reg cap, no spill).
//  blockIdx 0..31  : policy obs-encode (1024 rows)  -> enc_obs (f32)
//  blockIdx 32..63 : value net (1024 rows)          -> value   (f16)
//  blockIdx 64..   : act-encode on compacted rows   -> enc_act (f16, ws)
__global__ __launch_bounds__(512, 6)
void trunk_kernel(
    const f16* __restrict__ obs, const f16* __restrict__ xact,
    const int* __restrict__ vrows, const int* __restrict__ counter,
    const f16* __restrict__ packP, const f16* __restrict__ packV,
    // policy params
    const f16* __restrict__ pb_in, const f16* __restrict__ pg_in, const f16* __restrict__ pbe_in,
    const f16* __restrict__ pB, const f16* __restrict__ pG, const f16* __restrict__ pBe,
    const f16* __restrict__ po_b1, const f16* __restrict__ po_b2,
    // value params
    const f16* __restrict__ vb_in, const f16* __restrict__ vg_in, const f16* __restrict__ vbe_in,
    const f16* __restrict__ vB, const f16* __restrict__ vG, const f16* __restrict__ vBe,
    const f16* __restrict__ vo_b1, const f16* __restrict__ vo_b2, const f16* __restrict__ vo_w2,
    float* __restrict__ enc_obs_out, f16* __restrict__ enc_act_out,
    u16* __restrict__ value_out)
{
  __shared__ __align__(16) f16 h16[TROWS * 264];
  __shared__ __align__(16) float2 red[TROWS][8];
  __shared__ float2 stats[TROWS];

  const int tid  = threadIdx.x;
  const int lane = tid & 63;
  const int w    = tid >> 6;          // 0..7
  const int l15 = lane & 15, q = lane >> 4;
  const int n0 = w * 32;              // wave cols: w*32 .. w*32+31

  floatx4 acc[2][2];

  if (blockIdx.x >= 2 * OBS_BLOCKS) {
    // ---------------- act-encode role ----------------
    const int count = *counter;
    const int base = (blockIdx.x - 2 * OBS_BLOCKS) * TROWS;
    if (base >= count) return;

    for (int idx = tid; idx < TROWS * 128; idx += 512) {
      const int r = idx >> 7, c = idx & 127;
      const int gr = base + r;
      f16 v = (f16)0.f;
      if (c < E_DIM && gr < count) v = xact[(size_t)vrows[gr] * E_DIM + c];
      h16[r * 264 + c] = v;
    }
    __syncthreads();

    f16 res16[16];
    run_trunk<true>(packP, pb_in, pg_in, pbe_in, pB, pG, pBe, h16, red, stats,
                    acc, nullptr, res16, tid, q, l15, w, n0);
    policy_heads(packP, po_b1, po_b2, h16, acc, tid, q, l15, w, n0);

    const float* encf = (const float*)h16;
    for (int idx = tid; idx < TROWS * 112; idx += 512) {
      const int r = idx / 112, c = idx - r * 112;
      enc_act_out[(size_t)(base + r) * 112 + c] = (f16)encf[r * 112 + c];
    }
    return;
  }

  // ---------------- obs / value roles ----------------
  const bool isv = blockIdx.x >= OBS_BLOCKS;
  const int base = (isv ? (blockIdx.x - OBS_BLOCKS) : blockIdx.x) * TROWS;

  for (int idx = tid; idx < TROWS * 128; idx += 512) {
    const int r = idx >> 7, c = idx & 127;
    h16[r * 264 + c] = (c < E_DIM) ? obs[(size_t)(base + r) * E_DIM + c] : (f16)0.f;
  }
  __syncthreads();

  if (!isv) {
    f16 res16[16];
    run_trunk<true>(packP, pb_in, pg_in, pbe_in, pB, pG, pBe, h16, red, stats,
                    acc, nullptr, res16, tid, q, l15, w, n0);
    policy_heads(packP, po_b1, po_b2, h16, acc, tid, q, l15, w, n0);
    const float* encf = (const float*)h16;
    for (int idx = tid; idx < TROWS * E_DIM; idx += 512) {
      const int r = idx / E_DIM, c = idx - r * E_DIM;
      enc_obs_out[(size_t)(base + r) * E_DIM + c] = encf[r * 112 + c];
    }
  } else {
    float resf[16];
    run_trunk<false>(packV, vb_in, vg_in, vbe_in, vB, vG, vBe, h16, red, stats,
                     acc, resf, nullptr, tid, q, l15, w, n0);
    // value head1: relu(h @ vo_w1 + vo_b1), N=128 = 8 n-tiles, 1 per wave
    {
      const float bv = (float)vo_b1[w * 16 + l15];
      acc[0][0] = (floatx4){bv, bv, bv, bv};
      acc[1][0] = acc[0][0];
    }
    wave_gemm_t<8, 1, 8>(packV + NET_W1, h16, q, l15, lane, w, acc[0], acc[1]);
    __syncthreads();
    float* encf = (float*)h16;   // 32 x 128 fp32 (16384 B <= 16896 B)
#pragma unroll
    for (int mt = 0; mt < 2; ++mt)
#pragma unroll
      for (int reg = 0; reg < 4; ++reg) {
        const int R = mt * 16 + q * 4 + reg;
        encf[R * 128 + w * 16 + l15] = fmaxf(acc[mt][0][reg], 0.f);
      }
    __syncthreads();
    const float w2a = (float)vo_w2[lane], w2b = (float)vo_w2[lane + 64];
    const float b2v = (float)vo_b2[0];
    for (int j = 0; j < 4; ++j) {
      const int r = w * 4 + j;
      const float p = encf[r * 128 + lane] * w2a + encf[r * 128 + lane + 64] * w2b;
      const float tot = wsum(p);
      if (lane == 0) value_out[base + r] = f2h_u16(tot + b2v);
    }
  }
}

// epilogue: logits[vrow] = (enc_obs[bb] . enc_act[gr]) / sqrt(E)
__global__ __launch_bounds__(256)
void logits_kernel(const int* __restrict__ vrows, const int* __restrict__ counter,
                   const f16* __restrict__ enc_act, const float* __restrict__ enc_obs,
                   u16* __restrict__ logits)
{
  const int count = *counter;
  const int lane = threadIdx.x & 63;
  const int nw = (gridDim.x * blockDim.x) >> 6;
  for (int gr = (blockIdx.x * blockDim.x + threadIdx.x) >> 6; gr < count; gr += nw) {
    const int vrow = vrows[gr];
    const int bb = vrow >> 8;   // A = 256
    const float* ob = enc_obs + (size_t)bb * E_DIM;
    const f16*   ar = enc_act + (size_t)gr * 112;
    float p = (float)ar[lane] * ob[lane];
    if (lane + 64 < E_DIM) p += (float)ar[lane + 64] * ob[lane + 64];
    const float tot = wsum(p);
    if (lane == 0) logits[vrow] = f2h_u16(tot * 0.1f);   // 1/sqrt(100)
  }
}

// ============================ launch =======================================
extern "C" void kernel_launch(void* const* d_in, const int* in_sizes, int n_in,
                              void* d_out, int out_size, void* d_ws, size_t ws_size,
                              hipStream_t stream)
{
  const f16* obs   = (const f16*)d_in[0];
  const f16* actE  = (const f16*)d_in[1];
  const int* mask  = (const int*)d_in[2];
  const f16* pw_in = (const f16*)d_in[3];
  const f16* pb_in = (const f16*)d_in[4];
  const f16* pg_in = (const f16*)d_in[5];
  const f16* pbe_in= (const f16*)d_in[6];
  const f16* pW    = (const f16*)d_in[7];
  const f16* pB    = (const f16*)d_in[8];
  const f16* pG    = (const f16*)d_in[9];
  const f16* pBe   = (const f16*)d_in[10];
  const f16* po_w1 = (const f16*)d_in[11];
  const f16* po_b1 = (const f16*)d_in[12];
  const f16* po_w2 = (const f16*)d_in[13];
  const f16* po_b2 = (const f16*)d_in[14];
  const f16* vw_in = (const f16*)d_in[15];
  const f16* vb_in = (const f16*)d_in[16];
  const f16* vg_in = (const f16*)d_in[17];
  const f16* vbe_in= (const f16*)d_in[18];
  const f16* vW    = (const f16*)d_in[19];
  const f16* vB    = (const f16*)d_in[20];
  const f16* vG    = (const f16*)d_in[21];
  const f16* vBe   = (const f16*)d_in[22];
  const f16* vo_w1 = (const f16*)d_in[23];
  const f16* vo_b1 = (const f16*)d_in[24];
  const f16* vo_w2 = (const f16*)d_in[25];
  const f16* vo_b2 = (const f16*)d_in[26];

  u16* logits = (u16*)d_out;
  u16* value  = (u16*)d_out + NROWS_ACT;

  int*   counter = (int*)d_ws;
  int*   vrows   = (int*)((char*)d_ws + WS_VROWS);
  float* enc_obs = (float*)((char*)d_ws + WS_ENCOBS);
  f16*   packW   = (f16*)((char*)d_ws + WS_PACK);
  f16*   enc_act = (f16*)((char*)d_ws + WS_ENCACT);

  zero_counter_kernel<<<1, 1, 0, stream>>>(counter);
  compact_kernel<<<NROWS_ACT / 256, 256, 0, stream>>>(mask, NROWS_ACT, counter,
                                                      vrows, logits);
  pack_all_kernel<<<(PACK_TOTAL + 255) / 256, 256, 0, stream>>>(
      pw_in, pW, po_w1, po_w2, vw_in, vW, vo_w1, packW);

  trunk_kernel<<<ACT_BLOCKS + 2 * OBS_BLOCKS, 512, 0, stream>>>(
      obs, actE, vrows, counter, packW, packW + VAL_BASE,
      pb_in, pg_in, pbe_in, pB, pG, pBe, po_b1, po_b2,
      vb_in, vg_in, vbe_in, vB, vG, vBe, vo_b1, vo_b2, vo_w2,
      enc_obs, enc_act, value);

  logits_kernel<<<2048, 256, 0, stream>>>(vrows, counter, enc_act, enc_obs, logits);
}

// Round 9
// 464.105 us; speedup vs baseline: 1.0632x; 1.0318x over previous
//
#include <hip/hip_runtime.h>
#include <math.h>

// ---------------------------------------------------------------------------
// ActorCriticPolicy fused forward — FP16 in/out, fp32 internal (R6+ verified).
//   E=100, H=256, L=4 res blocks, B=1024, A=256.
//   d_out: logits (1024x256 fp16) then value (1024 fp16).
//
// R18: ping-pong unroll-2 GEMM k-loop. R17 went clean (no spill, 64% occ)
// and exposed the true regime: VALU-bound (VALUBusy 58.4 vs MfmaUtil 17.6,
// HBM 5%). Unroll-1 k-loop pays ~25-30 VALU/k-step of pure mechanics
// (8 v_mov ping-pong copies, 2x 64-bit pointer adds, per-load addressing)
// for 4 MFMAs. Two k-steps per iter with alternating b0/b1v kills the
// copies, halves pointer updates, immediate-offsets the 2nd A-read; last
// pair peeled (branch-free). Live set unchanged (16 VGPR of B-frags).
// Decisive: VALUBusy -> ~48-50, trunk -> ~230; FETCH/WRITE must stay
// ~29/75 MB (any jump = spill, revert).
//
// R17: (512,6) 80-reg cap = occupancy sweet spot; depth-1 B prefetch +
// f16 register residual, zero spill. VGPR 40+16 AGPR. trunk 254us.
// R16: unroll-1 k-loop (full-unroll hoisting was the spill source @cap64).
// R14: 8 waves x (32 rows x 32 cols); centralized LN stats (32-thr phase).
// R13/R12 lesson: spill poison — check FETCH/WRITE on every reg change.
// R11: ~225us residue is harness floor. R10: merged grid; logits epilogue.
//
// Wave w of 8: rows 0..31, cols w*32..+31 (2 n-tiles). A-frags from LDS
// h16[32][264]; B-frags from packed global (L2-resident), depth-1 prefetch.
// Fragment layouts (R7-verified): A: m=lane&15, k=(lane>>4)*8+j;
// B: n=lane&15, k=(lane>>4)*8+j; C/D: col=lane&15, row=(lane>>4)*4+reg.
//
// Packed layout (f16 units), per net [WIN | L0..L3 | W1head]:
//   policy: 0 win, 32768+l*65536 layers, W1@294912 (16 nt), W2@360448 (7 nt)
//   value:  base 389120: win, layers, W1@+294912 (8 nt). total 716800 f16.
// ---------------------------------------------------------------------------

typedef unsigned short u16;
typedef _Float16 f16;
typedef _Float16 half8 __attribute__((ext_vector_type(8)));
typedef float floatx4 __attribute__((ext_vector_type(4)));

#define E_DIM  100
#define H_DIM  256
#define NLAYER 4
#define BATCH  1024
#define NACT   256
#define NROWS_ACT (BATCH * NACT)
#define LN_EPS 1e-5f

#define NET_WIN  0
#define NET_WL(l) (32768 + (l) * 65536)
#define NET_W1   294912
#define NET_W2P  360448
#define POL_SZ   389120
#define VAL_BASE POL_SZ
#define PACK_TOTAL (POL_SZ + 327680)

#define TROWS 32                         // rows per block
#define ACT_BLOCKS (NROWS_ACT / TROWS)   // 8192
#define OBS_BLOCKS (BATCH / TROWS)       // 32 (policy) + 32 (value)

#define WS_VROWS   16
#define WS_ENCOBS  (16 + NROWS_ACT * 4)
#define WS_PACK    (WS_ENCOBS + BATCH * E_DIM * 4)
#define WS_ENCACT  (WS_PACK + PACK_TOTAL * 2)   // f16[NROWS_ACT * 112] ~ 59 MB

__device__ __forceinline__ u16 f2h_u16(float f) {
  union { u16 u; f16 h; } c; c.h = (f16)f; return c.u;
}

__device__ __forceinline__ float wsum(float v) {
#pragma unroll
  for (int off = 1; off < 64; off <<= 1) v += __shfl_xor(v, off, 64);
  return v;
}

// DPP 16-lane butterfly sum — VALU-only, no DS pipe traffic.
template <int CTRL>
__device__ __forceinline__ float dpp_add(float v) {
  const int t = __builtin_amdgcn_update_dpp(0, __float_as_int(v), CTRL, 0xF, 0xF, true);
  return v + __int_as_float(t);
}
__device__ __forceinline__ float dpp_red16(float v) {
  v = dpp_add<0xB1>(v);    // quad_perm [1,0,3,2]  (xor 1)
  v = dpp_add<0x4E>(v);    // quad_perm [2,3,0,1]  (xor 2)
  v = dpp_add<0x141>(v);   // row_half_mirror      (pairs 4-blocks)
  v = dpp_add<0x140>(v);   // row_mirror           (pairs 8-blocks)
  return v;
}

__global__ void zero_counter_kernel(int* counter) { *counter = 0; }

// Wave-aggregated compaction (R11; neutral vs per-lane atomic but keep).
__global__ void compact_kernel(const int* __restrict__ mask, int n,
                               int* __restrict__ counter,
                               int* __restrict__ rows,
                               u16* __restrict__ logits)
{
  const int i = blockIdx.x * blockDim.x + threadIdx.x;
  const int lane = threadIdx.x & 63;
  bool valid = false;
  if (i < n) {
    valid = (mask[i] != 0);
    if (!valid) logits[i] = (u16)0xFBFF;   // -65504, finite fp16 -inf stand-in
  }
  const unsigned long long bal = __ballot(valid);
  const int cnt = __popcll(bal);
  int base = 0;
  if (lane == 0 && cnt) base = atomicAdd(counter, cnt);
  base = __shfl(base, 0, 64);
  if (valid) {
    const int off = __popcll(bal & ((1ull << lane) - 1ull));
    rows[base + off] = i;
  }
}

__device__ __forceinline__ f16 pack_elem(const f16* __restrict__ W, int li,
                                         int K, int N, int Np)
{
  const int j = li & 7, lane = (li >> 3) & 63, tile = li >> 9;
  const int ntiles = Np >> 4;
  const int k0 = (tile / ntiles) * 32, n0 = (tile % ntiles) * 16;
  const int k = k0 + ((lane >> 4) << 3) + j, n = n0 + (lane & 15);
  return (k < K && n < N) ? W[k * N + n] : (f16)0.f;
}

__global__ void pack_all_kernel(
    const f16* __restrict__ pw_in, const f16* __restrict__ pW,
    const f16* __restrict__ po_w1, const f16* __restrict__ po_w2,
    const f16* __restrict__ vw_in, const f16* __restrict__ vW,
    const f16* __restrict__ vo_w1, f16* __restrict__ dst)
{
  const int i = blockIdx.x * blockDim.x + threadIdx.x;
  if (i >= PACK_TOTAL) return;
  f16 v;
  if (i < 32768)        v = pack_elem(pw_in, i, E_DIM, H_DIM, 256);
  else if (i < 294912) { const int r = i - 32768, l = r >> 16;
                         v = pack_elem(pW + (size_t)l * 65536, r & 65535, 256, 256, 256); }
  else if (i < 360448)  v = pack_elem(po_w1, i - 294912, 256, 256, 256);
  else if (i < 389120)  v = pack_elem(po_w2, i - 360448, 256, E_DIM, 112);
  else if (i < 421888)  v = pack_elem(vw_in, i - 389120, E_DIM, H_DIM, 256);
  else if (i < 684032) { const int r = i - 421888, l = r >> 16;
                         v = pack_elem(vW + (size_t)l * 65536, r & 65535, 256, 256, 256); }
  else                  v = pack_elem(vo_w1, i - 684032, 256, 128, 128);
  dst[i] = v;
}

// wave GEMM: KT k-steps of 32 (KT even), NTC n-tiles, NTA = total n-tiles.
// R18: ping-pong unroll-2 — two k-steps/iter alternating b0/b1v (no copies,
// half the pointer updates, imm-offset 2nd A-read). Last pair peeled.
template <int KT, int NTC, int NTA>
__device__ __forceinline__ void wave_gemm_t(
    const f16* __restrict__ pw, const f16* __restrict__ h16,
    int q, int l15, int lane, int nt_base,
    floatx4 acc0[], floatx4 acc1[])
{
  static_assert((KT & 1) == 0, "KT must be even");
  const f16* pl = pw + (size_t)nt_base * 512 + lane * 8;
  const f16* pa = h16 + l15 * 264 + q * 8;
  const size_t KS = (size_t)NTA * 512;
  half8 b0[NTC], b1[NTC];
#pragma unroll
  for (int t = 0; t < NTC; ++t) b0[t] = *(const half8*)(pl + t * 512);
#pragma unroll 1
  for (int kp = 0; kp < KT / 2 - 1; ++kp) {
#pragma unroll
    for (int t = 0; t < NTC; ++t) b1[t] = *(const half8*)(pl + KS + t * 512);
    {
      const half8 a0 = *(const half8*)(pa);
      const half8 a1 = *(const half8*)(pa + 16 * 264);
#pragma unroll
      for (int t = 0; t < NTC; ++t) {
        acc0[t] = __builtin_amdgcn_mfma_f32_16x16x32_f16(a0, b0[t], acc0[t], 0, 0, 0);
        acc1[t] = __builtin_amdgcn_mfma_f32_16x16x32_f16(a1, b0[t], acc1[t], 0, 0, 0);
      }
    }
#pragma unroll
    for (int t = 0; t < NTC; ++t) b0[t] = *(const half8*)(pl + 2 * KS + t * 512);
    {
      const half8 a0 = *(const half8*)(pa + 32);
      const half8 a1 = *(const half8*)(pa + 16 * 264 + 32);
#pragma unroll
      for (int t = 0; t < NTC; ++t) {
        acc0[t] = __builtin_amdgcn_mfma_f32_16x16x32_f16(a0, b1[t], acc0[t], 0, 0, 0);
        acc1[t] = __builtin_amdgcn_mfma_f32_16x16x32_f16(a1, b1[t], acc1[t], 0, 0, 0);
      }
    }
    pl += 2 * KS;
    pa += 64;
  }
  // final pair (no further prefetch)
#pragma unroll
  for (int t = 0; t < NTC; ++t) b1[t] = *(const half8*)(pl + KS + t * 512);
  {
    const half8 a0 = *(const half8*)(pa);
    const half8 a1 = *(const half8*)(pa + 16 * 264);
#pragma unroll
    for (int t = 0; t < NTC; ++t) {
      acc0[t] = __builtin_amdgcn_mfma_f32_16x16x32_f16(a0, b0[t], acc0[t], 0, 0, 0);
      acc1[t] = __builtin_amdgcn_mfma_f32_16x16x32_f16(a1, b0[t], acc1[t], 0, 0, 0);
    }
  }
  {
    const half8 a0 = *(const half8*)(pa + 32);
    const half8 a1 = *(const half8*)(pa + 16 * 264 + 32);
#pragma unroll
    for (int t = 0; t < NTC; ++t) {
      acc0[t] = __builtin_amdgcn_mfma_f32_16x16x32_f16(a0, b1[t], acc0[t], 0, 0, 0);
      acc1[t] = __builtin_amdgcn_mfma_f32_16x16x32_f16(a1, b1[t], acc1[t], 0, 0, 0);
    }
  }
}

// trunk: input layer + NLAYER residual layers.
// RREG=true: residual in f16 registers (policy). false: fp32 resf (value).
// 8 waves; wave w: rows 0..31, cols w*32..+31. 3 barriers/layer.
template <bool RREG>
__device__ __forceinline__ void run_trunk(
    const f16* __restrict__ packN,
    const f16* __restrict__ b_in, const f16* __restrict__ g_in, const f16* __restrict__ be_in,
    const f16* __restrict__ Br, const f16* __restrict__ Gr, const f16* __restrict__ Ber,
    f16* __restrict__ h16, float2 (*red)[8], float2* __restrict__ stats,
    floatx4 acc[2][2], float* __restrict__ resf, f16* __restrict__ res16,
    int tid, int q, int l15, int w, int n0)
{
#pragma unroll 1
  for (int l = 0; l <= NLAYER; ++l) {
    const f16* pw; const f16* bias; const f16* g; const f16* be;
    if (l == 0) { pw = packN + NET_WIN; bias = b_in; g = g_in; be = be_in; }
    else {
      pw = packN + NET_WL(l - 1); bias = Br + (l - 1) * H_DIM;
      g = Gr + (l - 1) * H_DIM;   be = Ber + (l - 1) * H_DIM;
    }
#pragma unroll
    for (int t = 0; t < 2; ++t) {
      const float bv = (float)bias[n0 + t * 16 + l15];
      acc[0][t] = (floatx4){bv, bv, bv, bv};
      acc[1][t] = acc[0][t];
    }
    if (l == 0) wave_gemm_t<4, 2, 16>(pw, h16, q, l15, tid & 63, w * 2, acc[0], acc[1]);
    else        wave_gemm_t<8, 2, 16>(pw, h16, q, l15, tid & 63, w * 2, acc[0], acc[1]);

    // partial sums over this wave's 32 cols
#pragma unroll
    for (int mt = 0; mt < 2; ++mt)
#pragma unroll
      for (int reg = 0; reg < 4; ++reg) {
        const float v0 = fmaxf(acc[mt][0][reg], 0.f);
        const float v1 = fmaxf(acc[mt][1][reg], 0.f);
        acc[mt][0][reg] = v0; acc[mt][1][reg] = v1;   // keep relu'd
        float s  = dpp_red16(v0 + v1);
        float s2 = dpp_red16(v0 * v0 + v1 * v1);
        if (l15 == 0) red[mt * 16 + q * 4 + reg][w] = (float2){s, s2};
      }
    __syncthreads();

    // centralized row stats: 32 threads, one row each
    if (tid < TROWS) {
      const float4* rp = (const float4*)&red[tid][0];
      const float4 r0 = rp[0], r1 = rp[1], r2 = rp[2], r3 = rp[3];
      const float s  = r0.x + r0.z + r1.x + r1.z + r2.x + r2.z + r3.x + r3.z;
      const float s2 = r0.y + r0.w + r1.y + r1.w + r2.y + r2.w + r3.y + r3.w;
      const float mean = s * (1.f / 256.f);
      const float var  = s2 * (1.f / 256.f) - mean * mean;
      stats[tid] = (float2){mean, 1.f / sqrtf(var + LN_EPS)};
    }
    __syncthreads();

    const float gf0 = (float)g[n0 + l15],       gf1 = (float)g[n0 + 16 + l15];
    const float bf0 = (float)be[n0 + l15],      bf1 = (float)be[n0 + 16 + l15];
#pragma unroll
    for (int mt = 0; mt < 2; ++mt)
#pragma unroll
      for (int reg = 0; reg < 4; ++reg) {
        const int R = mt * 16 + q * 4 + reg;
        const float2 st = stats[R];
#pragma unroll
        for (int t = 0; t < 2; ++t) {
          const int col = n0 + t * 16 + l15;
          const int ri = (mt * 2 + t) * 4 + reg;
          const float vv = (acc[mt][t][reg] - st.x) * st.y *
                           (t == 0 ? gf0 : gf1) + (t == 0 ? bf0 : bf1);
          float rprev;
          if (l == 0) rprev = 0.f;
          else rprev = RREG ? (float)res16[ri] : resf[ri];
          const float r = rprev + vv;
          if (RREG) res16[ri] = (f16)r; else resf[ri] = r;
          h16[R * 264 + col] = (f16)r;
        }
      }
    __syncthreads();
  }
}

// policy heads: h1 = relu(h @ w1 + b1); enc = h1 @ w2 + b2 -> encf (32x112 f32)
__device__ __forceinline__ void policy_heads(
    const f16* __restrict__ packN,
    const f16* __restrict__ b1, const f16* __restrict__ b2,
    f16* __restrict__ h16, floatx4 acc[2][2],
    int tid, int q, int l15, int w, int n0)
{
#pragma unroll
  for (int t = 0; t < 2; ++t) {
    const float bv = (float)b1[n0 + t * 16 + l15];
    acc[0][t] = (floatx4){bv, bv, bv, bv};
    acc[1][t] = acc[0][t];
  }
  wave_gemm_t<8, 2, 16>(packN + NET_W1, h16, q, l15, tid & 63, w * 2, acc[0], acc[1]);
  __syncthreads();
#pragma unroll
  for (int mt = 0; mt < 2; ++mt)
#pragma unroll
    for (int reg = 0; reg < 4; ++reg) {
      const int R = mt * 16 + q * 4 + reg;
#pragma unroll
      for (int t = 0; t < 2; ++t)
        h16[R * 264 + n0 + t * 16 + l15] = (f16)fmaxf(acc[mt][t][reg], 0.f);
    }
  __syncthreads();

  // W2: 7 n-tiles; waves 0..6 take one tile each
  if (w < 7) {
    const int col = w * 16 + l15;
    const float bv = (col < E_DIM) ? (float)b2[col] : 0.f;
    acc[0][0] = (floatx4){bv, bv, bv, bv};
    acc[1][0] = acc[0][0];
    wave_gemm_t<8, 1, 7>(packN + NET_W2P, h16, q, l15, tid & 63, w, acc[0], acc[1]);
  }
  __syncthreads();

  float* encf = (float*)h16;   // 32 x 112 fp32 (14336 B <= 16896 B)
  if (w < 7) {
#pragma unroll
    for (int mt = 0; mt < 2; ++mt)
#pragma unroll
      for (int reg = 0; reg < 4; ++reg) {
        const int R = mt * 16 + q * 4 + reg;
        encf[R * 112 + w * 16 + l15] = acc[mt][0][reg];
      }
  }
  __syncthreads();
}

// Merged trunk kernel (8 waves, 32 rows per block, 80-reg cap, no spill).
//  blockIdx 0..31  : policy obs-encode (1024 rows)  -> enc_obs (f32)
//  blockIdx 32..63 : value net (1024 rows)          -> value   (f16)
//  blockIdx 64..   : act-encode on compacted rows   -> enc_act (f16, ws)
__global__ __launch_bounds__(512, 6)
void trunk_kernel(
    const f16* __restrict__ obs, const f16* __restrict__ xact,
    const int* __restrict__ vrows, const int* __restrict__ counter,
    const f16* __restrict__ packP, const f16* __restrict__ packV,
    // policy params
    const f16* __restrict__ pb_in, const f16* __restrict__ pg_in, const f16* __restrict__ pbe_in,
    const f16* __restrict__ pB, const f16* __restrict__ pG, const f16* __restrict__ pBe,
    const f16* __restrict__ po_b1, const f16* __restrict__ po_b2,
    // value params
    const f16* __restrict__ vb_in, const f16* __restrict__ vg_in, const f16* __restrict__ vbe_in,
    const f16* __restrict__ vB, const f16* __restrict__ vG, const f16* __restrict__ vBe,
    const f16* __restrict__ vo_b1, const f16* __restrict__ vo_b2, const f16* __restrict__ vo_w2,
    float* __restrict__ enc_obs_out, f16* __restrict__ enc_act_out,
    u16* __restrict__ value_out)
{
  __shared__ __align__(16) f16 h16[TROWS * 264];
  __shared__ __align__(16) float2 red[TROWS][8];
  __shared__ float2 stats[TROWS];

  const int tid  = threadIdx.x;
  const int lane = tid & 63;
  const int w    = tid >> 6;          // 0..7
  const int l15 = lane & 15, q = lane >> 4;
  const int n0 = w * 32;              // wave cols: w*32 .. w*32+31

  floatx4 acc[2][2];

  if (blockIdx.x >= 2 * OBS_BLOCKS) {
    // ---------------- act-encode role ----------------
    const int count = *counter;
    const int base = (blockIdx.x - 2 * OBS_BLOCKS) * TROWS;
    if (base >= count) return;

    for (int idx = tid; idx < TROWS * 128; idx += 512) {
      const int r = idx >> 7, c = idx & 127;
      const int gr = base + r;
      f16 v = (f16)0.f;
      if (c < E_DIM && gr < count) v = xact[(size_t)vrows[gr] * E_DIM + c];
      h16[r * 264 + c] = v;
    }
    __syncthreads();

    f16 res16[16];
    run_trunk<true>(packP, pb_in, pg_in, pbe_in, pB, pG, pBe, h16, red, stats,
                    acc, nullptr, res16, tid, q, l15, w, n0);
    policy_heads(packP, po_b1, po_b2, h16, acc, tid, q, l15, w, n0);

    const float* encf = (const float*)h16;
    for (int idx = tid; idx < TROWS * 112; idx += 512) {
      const int r = idx / 112, c = idx - r * 112;
      enc_act_out[(size_t)(base + r) * 112 + c] = (f16)encf[r * 112 + c];
    }
    return;
  }

  // ---------------- obs / value roles ----------------
  const bool isv = blockIdx.x >= OBS_BLOCKS;
  const int base = (isv ? (blockIdx.x - OBS_BLOCKS) : blockIdx.x) * TROWS;

  for (int idx = tid; idx < TROWS * 128; idx += 512) {
    const int r = idx >> 7, c = idx & 127;
    h16[r * 264 + c] = (c < E_DIM) ? obs[(size_t)(base + r) * E_DIM + c] : (f16)0.f;
  }
  __syncthreads();

  if (!isv) {
    f16 res16[16];
    run_trunk<true>(packP, pb_in, pg_in, pbe_in, pB, pG, pBe, h16, red, stats,
                    acc, nullptr, res16, tid, q, l15, w, n0);
    policy_heads(packP, po_b1, po_b2, h16, acc, tid, q, l15, w, n0);
    const float* encf = (const float*)h16;
    for (int idx = tid; idx < TROWS * E_DIM; idx += 512) {
      const int r = idx / E_DIM, c = idx - r * E_DIM;
      enc_obs_out[(size_t)(base + r) * E_DIM + c] = encf[r * 112 + c];
    }
  } else {
    float resf[16];
    run_trunk<false>(packV, vb_in, vg_in, vbe_in, vB, vG, vBe, h16, red, stats,
                     acc, resf, nullptr, tid, q, l15, w, n0);
    // value head1: relu(h @ vo_w1 + vo_b1), N=128 = 8 n-tiles, 1 per wave
    {
      const float bv = (float)vo_b1[w * 16 + l15];
      acc[0][0] = (floatx4){bv, bv, bv, bv};
      acc[1][0] = acc[0][0];
    }
    wave_gemm_t<8, 1, 8>(packV + NET_W1, h16, q, l15, lane, w, acc[0], acc[1]);
    __syncthreads();
    float* encf = (float*)h16;   // 32 x 128 fp32 (16384 B <= 16896 B)
#pragma unroll
    for (int mt = 0; mt < 2; ++mt)
#pragma unroll
      for (int reg = 0; reg < 4; ++reg) {
        const int R = mt * 16 + q * 4 + reg;
        encf[R * 128 + w * 16 + l15] = fmaxf(acc[mt][0][reg], 0.f);
      }
    __syncthreads();
    const float w2a = (float)vo_w2[lane], w2b = (float)vo_w2[lane + 64];
    const float b2v = (float)vo_b2[0];
    for (int j = 0; j < 4; ++j) {
      const int r = w * 4 + j;
      const float p = encf[r * 128 + lane] * w2a + encf[r * 128 + lane + 64] * w2b;
      const float tot = wsum(p);
      if (lane == 0) value_out[base + r] = f2h_u16(tot + b2v);
    }
  }
}

// epilogue: logits[vrow] = (enc_obs[bb] . enc_act[gr]) / sqrt(E)
__global__ __launch_bounds__(256)
void logits_kernel(const int* __restrict__ vrows, const int* __restrict__ counter,
                   const f16* __restrict__ enc_act, const float* __restrict__ enc_obs,
                   u16* __restrict__ logits)
{
  const int count = *counter;
  const int lane = threadIdx.x & 63;
  const int nw = (gridDim.x * blockDim.x) >> 6;
  for (int gr = (blockIdx.x * blockDim.x + threadIdx.x) >> 6; gr < count; gr += nw) {
    const int vrow = vrows[gr];
    const int bb = vrow >> 8;   // A = 256
    const float* ob = enc_obs + (size_t)bb * E_DIM;
    const f16*   ar = enc_act + (size_t)gr * 112;
    float p = (float)ar[lane] * ob[lane];
    if (lane + 64 < E_DIM) p += (float)ar[lane + 64] * ob[lane + 64];
    const float tot = wsum(p);
    if (lane == 0) logits[vrow] = f2h_u16(tot * 0.1f);   // 1/sqrt(100)
  }
}

// ============================ launch =======================================
extern "C" void kernel_launch(void* const* d_in, const int* in_sizes, int n_in,
                              void* d_out, int out_size, void* d_ws, size_t ws_size,
                              hipStream_t stream)
{
  const f16* obs   = (const f16*)d_in[0];
  const f16* actE  = (const f16*)d_in[1];
  const int* mask  = (const int*)d_in[2];
  const f16* pw_in = (const f16*)d_in[3];
  const f16* pb_in = (const f16*)d_in[4];
  const f16* pg_in = (const f16*)d_in[5];
  const f16* pbe_in= (const f16*)d_in[6];
  const f16* pW    = (const f16*)d_in[7];
  const f16* pB    = (const f16*)d_in[8];
  const f16* pG    = (const f16*)d_in[9];
  const f16* pBe   = (const f16*)d_in[10];
  const f16* po_w1 = (const f16*)d_in[11];
  const f16* po_b1 = (const f16*)d_in[12];
  const f16* po_w2 = (const f16*)d_in[13];
  const f16* po_b2 = (const f16*)d_in[14];
  const f16* vw_in = (const f16*)d_in[15];
  const f16* vb_in = (const f16*)d_in[16];
  const f16* vg_in = (const f16*)d_in[17];
  const f16* vbe_in= (const f16*)d_in[18];
  const f16* vW    = (const f16*)d_in[19];
  const f16* vB    = (const f16*)d_in[20];
  const f16* vG    = (const f16*)d_in[21];
  const f16* vBe   = (const f16*)d_in[22];
  const f16* vo_w1 = (const f16*)d_in[23];
  const f16* vo_b1 = (const f16*)d_in[24];
  const f16* vo_w2 = (const f16*)d_in[25];
  const f16* vo_b2 = (const f16*)d_in[26];

  u16* logits = (u16*)d_out;
  u16* value  = (u16*)d_out + NROWS_ACT;

  int*   counter = (int*)d_ws;
  int*   vrows   = (int*)((char*)d_ws + WS_VROWS);
  float* enc_obs = (float*)((char*)d_ws + WS_ENCOBS);
  f16*   packW   = (f16*)((char*)d_ws + WS_PACK);
  f16*   enc_act = (f16*)((char*)d_ws + WS_ENCACT);

  zero_counter_kernel<<<1, 1, 0, stream>>>(counter);
  compact_kernel<<<NROWS_ACT / 256, 256, 0, stream>>>(mask, NROWS_ACT, counter,
                                                      vrows, logits);
  pack_all_kernel<<<(PACK_TOTAL + 255) / 256, 256, 0, stream>>>(
      pw_in, pW, po_w1, po_w2, vw_in, vW, vo_w1, packW);

  trunk_kernel<<<ACT_BLOCKS + 2 * OBS_BLOCKS, 512, 0, stream>>>(
      obs, actE, vrows, counter, packW, packW + VAL_BASE,
      pb_in, pg_in, pbe_in, pB, pG, pBe, po_b1, po_b2,
      vb_in, vg_in, vbe_in, vB, vG, vBe, vo_b1, vo_b2, vo_w2,
      enc_obs, enc_act, value);

  logits_kernel<<<2048, 256, 0, stream>>>(vrows, counter, enc_act, enc_obs, logits);
}

// Round 10
// 459.240 us; speedup vs baseline: 1.0744x; 1.0106x over previous
//
#include <hip/hip_runtime.h>
#include <math.h>

// ---------------------------------------------------------------------------
// ActorCriticPolicy fused forward — FP16 in/out, fp32 internal (R6+ verified).
//   E=100, H=256, L=4 res blocks, B=1024, A=256.
//   d_out: logits (1024x256 fp16) then value (1024 fp16).
//
// R19: VALU diet. R18 confirmed VALU-bound (49.9% busy vs MFMA 18.3).
//  (1) LN reduce: 2-step DPP (quad sums) instead of 4-step; quad leaders
//      (l15%4==0) write partials to red[32][32]; 32-thread stats phase sums
//      32 partials/row (serialization hidden by 2 other resident blocks).
//      Saves 32 fused-dpp ops/thread/layer in the all-waves-busy phase.
//  (2) LN apply in fma form: a=rstd*g, b=be-mean*a precomputed per (R,t),
//      then 1 fma/element.
//  (3) s_setprio(1) around MFMA bursts — 3 blocks/CU at independent phases
//      (T5 regime: role-diverse waves; NOT m190's lockstep null).
// Guard: VGPR<=48, FETCH/WRITE ~27/59 MB (jump = spill -> revert).
//
// R18: ping-pong unroll-2 GEMM k-loop (VALUBusy 58->50, trunk 254->242).
// R17: (512,6) 80-reg cap = occupancy sweet spot; depth-1 B prefetch +
// f16 register residual, zero spill. R16: unroll-1 (hoisting spilled @64).
// R13/R12 lesson: spill poison — check FETCH/WRITE on every reg change.
// R11: ~225us residue is harness floor. R10: merged grid; logits epilogue.
//
// Wave w of 8: rows 0..31, cols w*32..+31 (2 n-tiles). A-frags from LDS
// h16[32][264]; B-frags from packed global (L2-resident), depth-1 prefetch.
// Fragment layouts (R7-verified): A: m=lane&15, k=(lane>>4)*8+j;
// B: n=lane&15, k=(lane>>4)*8+j; C/D: col=lane&15, row=(lane>>4)*4+reg.
//
// Packed layout (f16 units), per net [WIN | L0..L3 | W1head]:
//   policy: 0 win, 32768+l*65536 layers, W1@294912 (16 nt), W2@360448 (7 nt)
//   value:  base 389120: win, layers, W1@+294912 (8 nt). total 716800 f16.
// ---------------------------------------------------------------------------

typedef unsigned short u16;
typedef _Float16 f16;
typedef _Float16 half8 __attribute__((ext_vector_type(8)));
typedef float floatx4 __attribute__((ext_vector_type(4)));

#define E_DIM  100
#define H_DIM  256
#define NLAYER 4
#define BATCH  1024
#define NACT   256
#define NROWS_ACT (BATCH * NACT)
#define LN_EPS 1e-5f

#define NET_WIN  0
#define NET_WL(l) (32768 + (l) * 65536)
#define NET_W1   294912
#define NET_W2P  360448
#define POL_SZ   389120
#define VAL_BASE POL_SZ
#define PACK_TOTAL (POL_SZ + 327680)

#define TROWS 32                         // rows per block
#define ACT_BLOCKS (NROWS_ACT / TROWS)   // 8192
#define OBS_BLOCKS (BATCH / TROWS)       // 32 (policy) + 32 (value)

#define WS_VROWS   16
#define WS_ENCOBS  (16 + NROWS_ACT * 4)
#define WS_PACK    (WS_ENCOBS + BATCH * E_DIM * 4)
#define WS_ENCACT  (WS_PACK + PACK_TOTAL * 2)   // f16[NROWS_ACT * 112] ~ 59 MB

__device__ __forceinline__ u16 f2h_u16(float f) {
  union { u16 u; f16 h; } c; c.h = (f16)f; return c.u;
}

__device__ __forceinline__ float wsum(float v) {
#pragma unroll
  for (int off = 1; off < 64; off <<= 1) v += __shfl_xor(v, off, 64);
  return v;
}

// DPP add — VALU-only, no DS pipe traffic.
template <int CTRL>
__device__ __forceinline__ float dpp_add(float v) {
  const int t = __builtin_amdgcn_update_dpp(0, __float_as_int(v), CTRL, 0xF, 0xF, true);
  return v + __int_as_float(t);
}
// 2-step quad sum: every lane gets the sum of its aligned quad (l15&~3).
__device__ __forceinline__ float dpp_red4(float v) {
  v = dpp_add<0xB1>(v);    // quad_perm [1,0,3,2]  (xor 1)
  v = dpp_add<0x4E>(v);    // quad_perm [2,3,0,1]  (xor 2)
  return v;
}

__global__ void zero_counter_kernel(int* counter) { *counter = 0; }

// Wave-aggregated compaction (R11; neutral vs per-lane atomic but keep).
__global__ void compact_kernel(const int* __restrict__ mask, int n,
                               int* __restrict__ counter,
                               int* __restrict__ rows,
                               u16* __restrict__ logits)
{
  const int i = blockIdx.x * blockDim.x + threadIdx.x;
  const int lane = threadIdx.x & 63;
  bool valid = false;
  if (i < n) {
    valid = (mask[i] != 0);
    if (!valid) logits[i] = (u16)0xFBFF;   // -65504, finite fp16 -inf stand-in
  }
  const unsigned long long bal = __ballot(valid);
  const int cnt = __popcll(bal);
  int base = 0;
  if (lane == 0 && cnt) base = atomicAdd(counter, cnt);
  base = __shfl(base, 0, 64);
  if (valid) {
    const int off = __popcll(bal & ((1ull << lane) - 1ull));
    rows[base + off] = i;
  }
}

__device__ __forceinline__ f16 pack_elem(const f16* __restrict__ W, int li,
                                         int K, int N, int Np)
{
  const int j = li & 7, lane = (li >> 3) & 63, tile = li >> 9;
  const int ntiles = Np >> 4;
  const int k0 = (tile / ntiles) * 32, n0 = (tile % ntiles) * 16;
  const int k = k0 + ((lane >> 4) << 3) + j, n = n0 + (lane & 15);
  return (k < K && n < N) ? W[k * N + n] : (f16)0.f;
}

__global__ void pack_all_kernel(
    const f16* __restrict__ pw_in, const f16* __restrict__ pW,
    const f16* __restrict__ po_w1, const f16* __restrict__ po_w2,
    const f16* __restrict__ vw_in, const f16* __restrict__ vW,
    const f16* __restrict__ vo_w1, f16* __restrict__ dst)
{
  const int i = blockIdx.x * blockDim.x + threadIdx.x;
  if (i >= PACK_TOTAL) return;
  f16 v;
  if (i < 32768)        v = pack_elem(pw_in, i, E_DIM, H_DIM, 256);
  else if (i < 294912) { const int r = i - 32768, l = r >> 16;
                         v = pack_elem(pW + (size_t)l * 65536, r & 65535, 256, 256, 256); }
  else if (i < 360448)  v = pack_elem(po_w1, i - 294912, 256, 256, 256);
  else if (i < 389120)  v = pack_elem(po_w2, i - 360448, 256, E_DIM, 112);
  else if (i < 421888)  v = pack_elem(vw_in, i - 389120, E_DIM, H_DIM, 256);
  else if (i < 684032) { const int r = i - 421888, l = r >> 16;
                         v = pack_elem(vW + (size_t)l * 65536, r & 65535, 256, 256, 256); }
  else                  v = pack_elem(vo_w1, i - 684032, 256, 128, 128);
  dst[i] = v;
}

// wave GEMM: KT k-steps of 32 (KT even), NTC n-tiles, NTA = total n-tiles.
// R18: ping-pong unroll-2. R19: setprio(1) around MFMA bursts (3 blocks/CU
// at independent phases -> CU scheduler can favor MFMA-issuing waves).
template <int KT, int NTC, int NTA>
__device__ __forceinline__ void wave_gemm_t(
    const f16* __restrict__ pw, const f16* __restrict__ h16,
    int q, int l15, int lane, int nt_base,
    floatx4 acc0[], floatx4 acc1[])
{
  static_assert((KT & 1) == 0, "KT must be even");
  const f16* pl = pw + (size_t)nt_base * 512 + lane * 8;
  const f16* pa = h16 + l15 * 264 + q * 8;
  const size_t KS = (size_t)NTA * 512;
  half8 b0[NTC], b1[NTC];
#pragma unroll
  for (int t = 0; t < NTC; ++t) b0[t] = *(const half8*)(pl + t * 512);
#pragma unroll 1
  for (int kp = 0; kp < KT / 2 - 1; ++kp) {
#pragma unroll
    for (int t = 0; t < NTC; ++t) b1[t] = *(const half8*)(pl + KS + t * 512);
    {
      const half8 a0 = *(const half8*)(pa);
      const half8 a1 = *(const half8*)(pa + 16 * 264);
      __builtin_amdgcn_s_setprio(1);
#pragma unroll
      for (int t = 0; t < NTC; ++t) {
        acc0[t] = __builtin_amdgcn_mfma_f32_16x16x32_f16(a0, b0[t], acc0[t], 0, 0, 0);
        acc1[t] = __builtin_amdgcn_mfma_f32_16x16x32_f16(a1, b0[t], acc1[t], 0, 0, 0);
      }
      __builtin_amdgcn_s_setprio(0);
    }
#pragma unroll
    for (int t = 0; t < NTC; ++t) b0[t] = *(const half8*)(pl + 2 * KS + t * 512);
    {
      const half8 a0 = *(const half8*)(pa + 32);
      const half8 a1 = *(const half8*)(pa + 16 * 264 + 32);
      __builtin_amdgcn_s_setprio(1);
#pragma unroll
      for (int t = 0; t < NTC; ++t) {
        acc0[t] = __builtin_amdgcn_mfma_f32_16x16x32_f16(a0, b1[t], acc0[t], 0, 0, 0);
        acc1[t] = __builtin_amdgcn_mfma_f32_16x16x32_f16(a1, b1[t], acc1[t], 0, 0, 0);
      }
      __builtin_amdgcn_s_setprio(0);
    }
    pl += 2 * KS;
    pa += 64;
  }
  // final pair (no further prefetch)
#pragma unroll
  for (int t = 0; t < NTC; ++t) b1[t] = *(const half8*)(pl + KS + t * 512);
  {
    const half8 a0 = *(const half8*)(pa);
    const half8 a1 = *(const half8*)(pa + 16 * 264);
    __builtin_amdgcn_s_setprio(1);
#pragma unroll
    for (int t = 0; t < NTC; ++t) {
      acc0[t] = __builtin_amdgcn_mfma_f32_16x16x32_f16(a0, b0[t], acc0[t], 0, 0, 0);
      acc1[t] = __builtin_amdgcn_mfma_f32_16x16x32_f16(a1, b0[t], acc1[t], 0, 0, 0);
    }
    __builtin_amdgcn_s_setprio(0);
  }
  {
    const half8 a0 = *(const half8*)(pa + 32);
    const half8 a1 = *(const half8*)(pa + 16 * 264 + 32);
    __builtin_amdgcn_s_setprio(1);
#pragma unroll
    for (int t = 0; t < NTC; ++t) {
      acc0[t] = __builtin_amdgcn_mfma_f32_16x16x32_f16(a0, b1[t], acc0[t], 0, 0, 0);
      acc1[t] = __builtin_amdgcn_mfma_f32_16x16x32_f16(a1, b1[t], acc1[t], 0, 0, 0);
    }
    __builtin_amdgcn_s_setprio(0);
  }
}

// trunk: input layer + NLAYER residual layers.
// RREG=true: residual in f16 registers (policy). false: fp32 resf (value).
// 8 waves; wave w: rows 0..31, cols w*32..+31. 3 barriers/layer.
template <bool RREG>
__device__ __forceinline__ void run_trunk(
    const f16* __restrict__ packN,
    const f16* __restrict__ b_in, const f16* __restrict__ g_in, const f16* __restrict__ be_in,
    const f16* __restrict__ Br, const f16* __restrict__ Gr, const f16* __restrict__ Ber,
    f16* __restrict__ h16, float2 (*red)[32], float2* __restrict__ stats,
    floatx4 acc[2][2], float* __restrict__ resf, f16* __restrict__ res16,
    int tid, int q, int l15, int w, int n0)
{
#pragma unroll 1
  for (int l = 0; l <= NLAYER; ++l) {
    const f16* pw; const f16* bias; const f16* g; const f16* be;
    if (l == 0) { pw = packN + NET_WIN; bias = b_in; g = g_in; be = be_in; }
    else {
      pw = packN + NET_WL(l - 1); bias = Br + (l - 1) * H_DIM;
      g = Gr + (l - 1) * H_DIM;   be = Ber + (l - 1) * H_DIM;
    }
#pragma unroll
    for (int t = 0; t < 2; ++t) {
      const float bv = (float)bias[n0 + t * 16 + l15];
      acc[0][t] = (floatx4){bv, bv, bv, bv};
      acc[1][t] = acc[0][t];
    }
    if (l == 0) wave_gemm_t<4, 2, 16>(pw, h16, q, l15, tid & 63, w * 2, acc[0], acc[1]);
    else        wave_gemm_t<8, 2, 16>(pw, h16, q, l15, tid & 63, w * 2, acc[0], acc[1]);

    // partial sums over this wave's 32 cols — 2-step DPP (quad sums),
    // quad leaders (l15%4==0) write red[R][w*4 + quad]
#pragma unroll
    for (int mt = 0; mt < 2; ++mt)
#pragma unroll
      for (int reg = 0; reg < 4; ++reg) {
        const float v0 = fmaxf(acc[mt][0][reg], 0.f);
        const float v1 = fmaxf(acc[mt][1][reg], 0.f);
        acc[mt][0][reg] = v0; acc[mt][1][reg] = v1;   // keep relu'd
        const float s  = dpp_red4(v0 + v1);
        const float s2 = dpp_red4(v0 * v0 + v1 * v1);
        if ((l15 & 3) == 0) {
          const int R = mt * 16 + q * 4 + reg;
          red[R][w * 4 + (l15 >> 2)] = (float2){s, s2};
        }
      }
    __syncthreads();

    // centralized row stats: 32 threads, one row each (32 partials/row)
    if (tid < TROWS) {
      const float4* rp = (const float4*)&red[tid][0];
      float s = 0.f, s2 = 0.f;
#pragma unroll
      for (int i = 0; i < 16; ++i) {
        const float4 r = rp[i];
        s += r.x + r.z; s2 += r.y + r.w;
      }
      const float mean = s * (1.f / 256.f);
      const float var  = s2 * (1.f / 256.f) - mean * mean;
      stats[tid] = (float2){mean, 1.f / sqrtf(var + LN_EPS)};
    }
    __syncthreads();

    const float gf0 = (float)g[n0 + l15],       gf1 = (float)g[n0 + 16 + l15];
    const float bf0 = (float)be[n0 + l15],      bf1 = (float)be[n0 + 16 + l15];
#pragma unroll
    for (int mt = 0; mt < 2; ++mt)
#pragma unroll
      for (int reg = 0; reg < 4; ++reg) {
        const int R = mt * 16 + q * 4 + reg;
        const float2 st = stats[R];
        const float a0c = st.y * gf0;
        const float b0c = fmaf(-st.x, a0c, bf0);
        const float a1c = st.y * gf1;
        const float b1c = fmaf(-st.x, a1c, bf1);
#pragma unroll
        for (int t = 0; t < 2; ++t) {
          const int col = n0 + t * 16 + l15;
          const int ri = (mt * 2 + t) * 4 + reg;
          const float vv = fmaf(acc[mt][t][reg],
                                t == 0 ? a0c : a1c, t == 0 ? b0c : b1c);
          float rprev;
          if (l == 0) rprev = 0.f;
          else rprev = RREG ? (float)res16[ri] : resf[ri];
          const float r = rprev + vv;
          if (RREG) res16[ri] = (f16)r; else resf[ri] = r;
          h16[R * 264 + col] = (f16)r;
        }
      }
    __syncthreads();
  }
}

// policy heads: h1 = relu(h @ w1 + b1); enc = h1 @ w2 + b2 -> encf (32x112 f32)
__device__ __forceinline__ void policy_heads(
    const f16* __restrict__ packN,
    const f16* __restrict__ b1, const f16* __restrict__ b2,
    f16* __restrict__ h16, floatx4 acc[2][2],
    int tid, int q, int l15, int w, int n0)
{
#pragma unroll
  for (int t = 0; t < 2; ++t) {
    const float bv = (float)b1[n0 + t * 16 + l15];
    acc[0][t] = (floatx4){bv, bv, bv, bv};
    acc[1][t] = acc[0][t];
  }
  wave_gemm_t<8, 2, 16>(packN + NET_W1, h16, q, l15, tid & 63, w * 2, acc[0], acc[1]);
  __syncthreads();
#pragma unroll
  for (int mt = 0; mt < 2; ++mt)
#pragma unroll
    for (int reg = 0; reg < 4; ++reg) {
      const int R = mt * 16 + q * 4 + reg;
#pragma unroll
      for (int t = 0; t < 2; ++t)
        h16[R * 264 + n0 + t * 16 + l15] = (f16)fmaxf(acc[mt][t][reg], 0.f);
    }
  __syncthreads();

  // W2: 7 n-tiles; waves 0..6 take one tile each
  if (w < 7) {
    const int col = w * 16 + l15;
    const float bv = (col < E_DIM) ? (float)b2[col] : 0.f;
    acc[0][0] = (floatx4){bv, bv, bv, bv};
    acc[1][0] = acc[0][0];
    wave_gemm_t<8, 1, 7>(packN + NET_W2P, h16, q, l15, tid & 63, w, acc[0], acc[1]);
  }
  __syncthreads();

  float* encf = (float*)h16;   // 32 x 112 fp32 (14336 B <= 16896 B)
  if (w < 7) {
#pragma unroll
    for (int mt = 0; mt < 2; ++mt)
#pragma unroll
      for (int reg = 0; reg < 4; ++reg) {
        const int R = mt * 16 + q * 4 + reg;
        encf[R * 112 + w * 16 + l15] = acc[mt][0][reg];
      }
  }
  __syncthreads();
}

// Merged trunk kernel (8 waves, 32 rows per block, 80-reg cap, no spill).
//  blockIdx 0..31  : policy obs-encode (1024 rows)  -> enc_obs (f32)
//  blockIdx 32..63 : value net (1024 rows)          -> value   (f16)
//  blockIdx 64..   : act-encode on compacted rows   -> enc_act (f16, ws)
__global__ __launch_bounds__(512, 6)
void trunk_kernel(
    const f16* __restrict__ obs, const f16* __restrict__ xact,
    const int* __restrict__ vrows, const int* __restrict__ counter,
    const f16* __restrict__ packP, const f16* __restrict__ packV,
    // policy params
    const f16* __restrict__ pb_in, const f16* __restrict__ pg_in, const f16* __restrict__ pbe_in,
    const f16* __restrict__ pB, const f16* __restrict__ pG, const f16* __restrict__ pBe,
    const f16* __restrict__ po_b1, const f16* __restrict__ po_b2,
    // value params
    const f16* __restrict__ vb_in, const f16* __restrict__ vg_in, const f16* __restrict__ vbe_in,
    const f16* __restrict__ vB, const f16* __restrict__ vG, const f16* __restrict__ vBe,
    const f16* __restrict__ vo_b1, const f16* __restrict__ vo_b2, const f16* __restrict__ vo_w2,
    float* __restrict__ enc_obs_out, f16* __restrict__ enc_act_out,
    u16* __restrict__ value_out)
{
  __shared__ __align__(16) f16 h16[TROWS * 264];
  __shared__ __align__(16) float2 red[TROWS][32];
  __shared__ float2 stats[TROWS];

  const int tid  = threadIdx.x;
  const int lane = tid & 63;
  const int w    = tid >> 6;          // 0..7
  const int l15 = lane & 15, q = lane >> 4;
  const int n0 = w * 32;              // wave cols: w*32 .. w*32+31

  floatx4 acc[2][2];

  if (blockIdx.x >= 2 * OBS_BLOCKS) {
    // ---------------- act-encode role ----------------
    const int count = *counter;
    const int base = (blockIdx.x - 2 * OBS_BLOCKS) * TROWS;
    if (base >= count) return;

    for (int idx = tid; idx < TROWS * 128; idx += 512) {
      const int r = idx >> 7, c = idx & 127;
      const int gr = base + r;
      f16 v = (f16)0.f;
      if (c < E_DIM && gr < count) v = xact[(size_t)vrows[gr] * E_DIM + c];
      h16[r * 264 + c] = v;
    }
    __syncthreads();

    f16 res16[16];
    run_trunk<true>(packP, pb_in, pg_in, pbe_in, pB, pG, pBe, h16, red, stats,
                    acc, nullptr, res16, tid, q, l15, w, n0);
    policy_heads(packP, po_b1, po_b2, h16, acc, tid, q, l15, w, n0);

    const float* encf = (const float*)h16;
    for (int idx = tid; idx < TROWS * 112; idx += 512) {
      const int r = idx / 112, c = idx - r * 112;
      enc_act_out[(size_t)(base + r) * 112 + c] = (f16)encf[r * 112 + c];
    }
    return;
  }

  // ---------------- obs / value roles ----------------
  const bool isv = blockIdx.x >= OBS_BLOCKS;
  const int base = (isv ? (blockIdx.x - OBS_BLOCKS) : blockIdx.x) * TROWS;

  for (int idx = tid; idx < TROWS * 128; idx += 512) {
    const int r = idx >> 7, c = idx & 127;
    h16[r * 264 + c] = (c < E_DIM) ? obs[(size_t)(base + r) * E_DIM + c] : (f16)0.f;
  }
  __syncthreads();

  if (!isv) {
    f16 res16[16];
    run_trunk<true>(packP, pb_in, pg_in, pbe_in, pB, pG, pBe, h16, red, stats,
                    acc, nullptr, res16, tid, q, l15, w, n0);
    policy_heads(packP, po_b1, po_b2, h16, acc, tid, q, l15, w, n0);
    const float* encf = (const float*)h16;
    for (int idx = tid; idx < TROWS * E_DIM; idx += 512) {
      const int r = idx / E_DIM, c = idx - r * E_DIM;
      enc_obs_out[(size_t)(base + r) * E_DIM + c] = encf[r * 112 + c];
    }
  } else {
    float resf[16];
    run_trunk<false>(packV, vb_in, vg_in, vbe_in, vB, vG, vBe, h16, red, stats,
                     acc, resf, nullptr, tid, q, l15, w, n0);
    // value head1: relu(h @ vo_w1 + vo_b1), N=128 = 8 n-tiles, 1 per wave
    {
      const float bv = (float)vo_b1[w * 16 + l15];
      acc[0][0] = (floatx4){bv, bv, bv, bv};
      acc[1][0] = acc[0][0];
    }
    wave_gemm_t<8, 1, 8>(packV + NET_W1, h16, q, l15, lane, w, acc[0], acc[1]);
    __syncthreads();
    float* encf = (float*)h16;   // 32 x 128 fp32 (16384 B <= 16896 B)
#pragma unroll
    for (int mt = 0; mt < 2; ++mt)
#pragma unroll
      for (int reg = 0; reg < 4; ++reg) {
        const int R = mt * 16 + q * 4 + reg;
        encf[R * 128 + w * 16 + l15] = fmaxf(acc[mt][0][reg], 0.f);
      }
    __syncthreads();
    const float w2a = (float)vo_w2[lane], w2b = (float)vo_w2[lane + 64];
    const float b2v = (float)vo_b2[0];
    for (int j = 0; j < 4; ++j) {
      const int r = w * 4 + j;
      const float p = encf[r * 128 + lane] * w2a + encf[r * 128 + lane + 64] * w2b;
      const float tot = wsum(p);
      if (lane == 0) value_out[base + r] = f2h_u16(tot + b2v);
    }
  }
}

// epilogue: logits[vrow] = (enc_obs[bb] . enc_act[gr]) / sqrt(E)
__global__ __launch_bounds__(256)
void logits_kernel(const int* __restrict__ vrows, const int* __restrict__ counter,
                   const f16* __restrict__ enc_act, const float* __restrict__ enc_obs,
                   u16* __restrict__ logits)
{
  const int count = *counter;
  const int lane = threadIdx.x & 63;
  const int nw = (gridDim.x * blockDim.x) >> 6;
  for (int gr = (blockIdx.x * blockDim.x + threadIdx.x) >> 6; gr < count; gr += nw) {
    const int vrow = vrows[gr];
    const int bb = vrow >> 8;   // A = 256
    const float* ob = enc_obs + (size_t)bb * E_DIM;
    const f16*   ar = enc_act + (size_t)gr * 112;
    float p = (float)ar[lane] * ob[lane];
    if (lane + 64 < E_DIM) p += (float)ar[lane + 64] * ob[lane + 64];
    const float tot = wsum(p);
    if (lane == 0) logits[vrow] = f2h_u16(tot * 0.1f);   // 1/sqrt(100)
  }
}

// ============================ launch =======================================
extern "C" void kernel_launch(void* const* d_in, const int* in_sizes, int n_in,
                              void* d_out, int out_size, void* d_ws, size_t ws_size,
                              hipStream_t stream)
{
  const f16* obs   = (const f16*)d_in[0];
  const f16* actE  = (const f16*)d_in[1];
  const int* mask  = (const int*)d_in[2];
  const f16* pw_in = (const f16*)d_in[3];
  const f16* pb_in = (const f16*)d_in[4];
  const f16* pg_in = (const f16*)d_in[5];
  const f16* pbe_in= (const f16*)d_in[6];
  const f16* pW    = (const f16*)d_in[7];
  const f16* pB    = (const f16*)d_in[8];
  const f16* pG    = (const f16*)d_in[9];
  const f16* pBe   = (const f16*)d_in[10];
  const f16* po_w1 = (const f16*)d_in[11];
  const f16* po_b1 = (const f16*)d_in[12];
  const f16* po_w2 = (const f16*)d_in[13];
  const f16* po_b2 = (const f16*)d_in[14];
  const f16* vw_in = (const f16*)d_in[15];
  const f16* vb_in = (const f16*)d_in[16];
  const f16* vg_in = (const f16*)d_in[17];
  const f16* vbe_in= (const f16*)d_in[18];
  const f16* vW    = (const f16*)d_in[19];
  const f16* vB    = (const f16*)d_in[20];
  const f16* vG    = (const f16*)d_in[21];
  const f16* vBe   = (const f16*)d_in[22];
  const f16* vo_w1 = (const f16*)d_in[23];
  const f16* vo_b1 = (const f16*)d_in[24];
  const f16* vo_w2 = (const f16*)d_in[25];
  const f16* vo_b2 = (const f16*)d_in[26];

  u16* logits = (u16*)d_out;
  u16* value  = (u16*)d_out + NROWS_ACT;

  int*   counter = (int*)d_ws;
  int*   vrows   = (int*)((char*)d_ws + WS_VROWS);
  float* enc_obs = (float*)((char*)d_ws + WS_ENCOBS);
  f16*   packW   = (f16*)((char*)d_ws + WS_PACK);
  f16*   enc_act = (f16*)((char*)d_ws + WS_ENCACT);

  zero_counter_kernel<<<1, 1, 0, stream>>>(counter);
  compact_kernel<<<NROWS_ACT / 256, 256, 0, stream>>>(mask, NROWS_ACT, counter,
                                                      vrows, logits);
  pack_all_kernel<<<(PACK_TOTAL + 255) / 256, 256, 0, stream>>>(
      pw_in, pW, po_w1, po_w2, vw_in, vW, vo_w1, packW);

  trunk_kernel<<<ACT_BLOCKS + 2 * OBS_BLOCKS, 512, 0, stream>>>(
      obs, actE, vrows, counter, packW, packW + VAL_BASE,
      pb_in, pg_in, pbe_in, pB, pG, pBe, po_b1, po_b2,
      vb_in, vg_in, vbe_in, vB, vG, vBe, vo_b1, vo_b2, vo_w2,
      enc_obs, enc_act, value);

  logits_kernel<<<2048, 256, 0, stream>>>(vrows, counter, enc_act, enc_obs, logits);
}